// Round 8
// baseline (647.228 us; speedup 1.0000x reference)
//
#include <hip/hip_runtime.h>
#include <hip/hip_bf16.h>
#include <math.h>

typedef __attribute__((ext_vector_type(8))) short short8v;
typedef __attribute__((ext_vector_type(4))) float f32x4;

// ---------------- ws layout ----------------
// float region:
#define F_S1 0
#define F_H1 32
#define F_S2 64
#define F_H2 128
#define F_S3 192
#define F_H3 320
#define F_S4 448
#define F_H4 704
#define F_B1 960
#define F_BAR 1008       // barrier counter (memset to 0 each replay)
#define F_P4 1024        // 128*200*4 floats
#define F_END (1024 + 128*200*4)
// bf16 region:
#define H_BASE (F_END*2)
#define H_P1  H_BASE                    // [t=256][s=128][c=32] (t<247 written)
#define H_WA1 (H_P1 + 128*8192)         // 32*640
#define H_WA2 (H_WA1 + 32*640)          // 64*320
#define H_WA3 (H_WA2 + 64*320)          // 112*640
#define H_WA4 (H_WA3 + 112*640)         // 208*1280
#define H_P2  (H_WA4 + 208*1280)        // [t=79][s=128][c=64]
#define H_P3  (H_P2 + 79*128*64)        // [t=23][s=128][c=128]

#define N_WA1 (32*640)
#define N_WA2 (64*320)
#define N_WA3 (112*640)
#define N_WA4 (208*1280)
#define N_WTOT (N_WA1 + N_WA2 + N_WA3 + N_WA4)

#define NBLK 512
#define NTHR 131072      // NBLK*256
#define NWAV 2048        // NBLK*4

__device__ __forceinline__ float eluf(float v) {
    return v > 0.f ? v : (expf(v) - 1.f);
}
__device__ __forceinline__ float ldh(const __hip_bfloat16* p) { return __bfloat162float(*p); }
__device__ __forceinline__ unsigned short bfb(float v) {
    __hip_bfloat16 h = __float2bfloat16(v);
    return reinterpret_cast<unsigned short&>(h);
}
__device__ __forceinline__ void ld4f(const float* p, float* v) {
    float2 a = *(const float2*)p, c = *(const float2*)(p + 2);
    v[0] = a.x; v[1] = a.y; v[2] = c.x; v[3] = c.y;
}

// device-scope grid barrier (all NBLK blocks co-resident by construction)
__device__ __forceinline__ void gbar(unsigned* bar, unsigned target) {
    __syncthreads();                 // drains each thread's vmem (vmcnt0) pre-barrier
    if (threadIdx.x == 0) {
        __hip_atomic_fetch_add(bar, 1u, __ATOMIC_ACQ_REL, __HIP_MEMORY_SCOPE_AGENT);
        while (__hip_atomic_load(bar, __ATOMIC_ACQUIRE, __HIP_MEMORY_SCOPE_AGENT) < target)
            __builtin_amdgcn_s_sleep(2);
    }
    __syncthreads();
}

// ---------------- the single persistent kernel ----------------
__global__ __launch_bounds__(256, 2) void k_mega(
    const float* __restrict__ x, const int* __restrict__ cids,
    const float* __restrict__ ct_w, const float* __restrict__ ct_b,
    const float* __restrict__ cs_w,
    const float* __restrict__ g1, const float* __restrict__ b1,
    const float* __restrict__ m1, const float* __restrict__ v1,
    const float* __restrict__ w2,
    const float* __restrict__ g2, const float* __restrict__ b2,
    const float* __restrict__ m2, const float* __restrict__ v2,
    const float* __restrict__ w3,
    const float* __restrict__ g3, const float* __restrict__ b3,
    const float* __restrict__ m3, const float* __restrict__ v3,
    const float* __restrict__ w4,
    const float* __restrict__ g4, const float* __restrict__ b4,
    const float* __restrict__ m4, const float* __restrict__ v4,
    const float* __restrict__ fcw, const float* __restrict__ fcb,
    const float* __restrict__ hW1, const float* __restrict__ hb1,
    const float* __restrict__ hW2, const float* __restrict__ hb2,
    float* __restrict__ ws, float* __restrict__ out) {
    __hip_bfloat16* wsh = (__hip_bfloat16*)ws;
    unsigned* bar = (unsigned*)(ws + F_BAR);
    int tid = threadIdx.x;
    int gtid = blockIdx.x * 256 + tid;
    int lane = tid & 63, wid = tid >> 6;
    int lo = lane & 15, kg = lane >> 4;
    int gw = blockIdx.x * 4 + wid;

    // LDS: conv1 phase uses xb(26624B)+eb(12288B); heads phase reuses front.
    __shared__ __align__(16) unsigned char smem[26624 + 12288];
    __hip_bfloat16* xb = (__hip_bfloat16*)smem;            // [208][64]
    __hip_bfloat16* eb = (__hip_bfloat16*)(smem + 26624);  // [32][192]

    // ================= phase 0: weight prep + BN affines =================
    for (int t = gtid; t < N_WTOT + 960; t += NTHR) {
        if (t < N_WA1) {
            int o = t / 640, kv = t - o * 640, kk = kv / 64, c = kv - kk * 64;
            float s = 0.f;
            if (o < 25)
                for (int i = 0; i < 25; ++i)
                    s += cs_w[(o * 25 + i) * 64 + c] * ct_w[i * 10 + kk];
            wsh[H_WA1 + t] = __float2bfloat16(s);
        } else if (t < N_WA1 + N_WA2) {
            int u = t - N_WA1;
            int o = u / 320, kv = u - o * 320, kk = kv / 32, c = kv - kk * 32;
            float s = (o < 50 && c < 25) ? w2[(o * 25 + c) * 10 + kk] : 0.f;
            wsh[H_WA2 + u] = __float2bfloat16(s);
        } else if (t < N_WA1 + N_WA2 + N_WA3) {
            int u = t - N_WA1 - N_WA2;
            int o = u / 640, kv = u - o * 640, kk = kv / 64, c = kv - kk * 64;
            float s = (o < 100 && c < 50) ? w3[(o * 50 + c) * 10 + kk] : 0.f;
            wsh[H_WA3 + u] = __float2bfloat16(s);
        } else if (t < N_WTOT) {
            int u = t - N_WA1 - N_WA2 - N_WA3;
            int o = u / 1280, kv = u - o * 1280, kk = kv / 128, c = kv - kk * 128;
            float s = (o < 200 && c < 100) ? w4[(o * 100 + c) * 10 + kk] : 0.f;
            wsh[H_WA4 + u] = __float2bfloat16(s);
        } else {
            int j = t - N_WTOT;
            if (j < 25) {
                float sc = g1[j] / sqrtf(v1[j] + 1e-5f);
                ws[F_S1 + j] = sc; ws[F_H1 + j] = b1[j] - m1[j] * sc;
            } else if (j >= 32 && j < 82) {
                int ch = j - 32;
                float sc = g2[ch] / sqrtf(v2[ch] + 1e-5f);
                ws[F_S2 + ch] = sc; ws[F_H2 + ch] = b2[ch] - m2[ch] * sc;
            } else if (j >= 96 && j < 196) {
                int ch = j - 96;
                float sc = g3[ch] / sqrtf(v3[ch] + 1e-5f);
                ws[F_S3 + ch] = sc; ws[F_H3 + ch] = b3[ch] - m3[ch] * sc;
            } else if (j >= 224 && j < 424) {
                int ch = j - 224;
                float sc = g4[ch] / sqrtf(v4[ch] + 1e-5f);
                ws[F_S4 + ch] = sc; ws[F_H4 + ch] = b4[ch] - m4[ch] * sc;
            } else if (j >= 448 && j < 473) {
                int o = j - 448;
                float s = 0.f;
                for (int i = 0; i < 25; ++i) {
                    float cs = 0.f;
                    for (int c = 0; c < 64; ++c) cs += cs_w[(o * 25 + i) * 64 + c];
                    s += cs * ct_b[i];
                }
                ws[F_B1 + o] = s;
            }
        }
    }
    gbar(bar, NBLK * 1);

    // ================= phase 1: conv1+BN+ELU+pool (1 tile/block) =========
    {
        int tile = blockIdx.x;            // 512 tiles = 4 t-tiles x 128 samples
        int b = tile >> 2, bx = tile & 3;
        int tp0 = 62 * bx;
        int PTb = min(62, 247 - tp0);     // 62,62,62,61
        int t0 = 186 * bx;

        for (int f = tid; f < 64 * 52; f += 256) {
            int c = f / 52, j = f - c * 52;
            int t = t0 + 4 * j;
            const float* src = x + ((size_t)b * 64 + c) * 750 + t;
            float v[4];
            if (t + 3 < 750) {
                ld4f(src, v);
            } else {
#pragma unroll
                for (int e = 0; e < 4; ++e) v[e] = (t + e < 750) ? src[e] : 0.f;
            }
#pragma unroll
            for (int e = 0; e < 4; ++e) {
                int r = 4 * j + e;
                xb[r * 64 + (c ^ (8 * (r & 7)))] = __float2bfloat16(v[e]);
            }
        }
        __syncthreads();

        int ot = wid >> 1, ctg = wid & 1;            // 2 ot x 2 ct-groups
        const short8v* Ap = (const short8v*)(wsh + H_WA1 + (size_t)(ot * 16 + lo) * 640);
        f32x4 acc[6];
#pragma unroll
        for (int q = 0; q < 6; ++q) acc[q] = (f32x4){0.f, 0.f, 0.f, 0.f};
#pragma unroll 1
        for (int sb = 0; sb < 20; sb += 10) {
            short8v af[10];
#pragma unroll
            for (int u = 0; u < 10; ++u) af[u] = Ap[(sb + u) * 4 + kg];
#pragma unroll
            for (int u = 0; u < 10; ++u) {
                int s = sb + u;
                int kk = s >> 1, cb = s & 1;
#pragma unroll
                for (int q = 0; q < 6; ++q) {
                    int r = (ctg * 6 + q) * 16 + lo + kk;
                    int cs = (cb * 32 + kg * 8) ^ (8 * (r & 7));
                    short8v bf = *(const short8v*)&xb[r * 64 + cs];
                    acc[q] = __builtin_amdgcn_mfma_f32_16x16x32_bf16(af[u], bf, acc[q], 0, 0, 0);
                }
            }
        }
#pragma unroll
        for (int q = 0; q < 6; ++q) {
            int tloc = (ctg * 6 + q) * 16 + lo;
#pragma unroll
            for (int e = 0; e < 4; ++e) {
                int o2 = ot * 16 + kg * 4 + e;       // < 32
                float a = acc[q][e] + ws[F_B1 + o2];
                eb[o2 * 192 + tloc] = __float2bfloat16(eluf(a * ws[F_S1 + o2] + ws[F_H1 + o2]));
            }
        }
        __syncthreads();

        __hip_bfloat16* p1g = wsh + H_P1;
        for (int i = tid; i < 8 * 62; i += 256) {
            int og = i / 62, pl = i - og * 62;
            if (pl < PTb) {
                int tp = tp0 + pl;
                unsigned short uv[4];
#pragma unroll
                for (int j = 0; j < 4; ++j) {
                    int o = og * 4 + j;
                    float v = 0.f;
                    if (o < 25) {
                        const __hip_bfloat16* ep = eb + o * 192 + 3 * pl;
                        v = fmaxf(fmaxf(ldh(ep), ldh(ep + 1)), ldh(ep + 2));
                    }
                    uv[j] = bfb(v);
                }
                uint2 pk = {(unsigned)uv[0] | ((unsigned)uv[1] << 16),
                            (unsigned)uv[2] | ((unsigned)uv[3] << 16)};
                *(uint2*)(p1g + (size_t)tp * 4096 + b * 32 + og * 4) = pk;
            }
        }
    }
    gbar(bar, NBLK * 2);

    // ================= phase 2: L2 GEMM (25->50) =========================
    {
        const __hip_bfloat16* p1 = wsh + H_P1;
        const __hip_bfloat16* W = wsh + H_WA2;
        __hip_bfloat16* p2 = wsh + H_P2;
        for (int w = gw; w < 2528; w += NWAV) {      // 632 cols x 4 ot
            int ot = w & 3, cw = w >> 2;
            int tp = cw >> 3, s0 = (cw & 7) * 16;
            const __hip_bfloat16* bbase = p1 + (size_t)(s0 + lo) * 32 + kg * 8;
            short8v B[12];
#pragma unroll
            for (int v = 0; v < 12; ++v)
                B[v] = *(const short8v*)(bbase + (size_t)(3 * tp + v) * 4096);
            f32x4 acc[3];
#pragma unroll
            for (int u = 0; u < 3; ++u) acc[u] = (f32x4){0.f, 0.f, 0.f, 0.f};
            const __hip_bfloat16* arow = W + (size_t)(ot * 16 + lo) * 320 + kg * 8;
#pragma unroll
            for (int kk = 0; kk < 10; ++kk) {
                short8v a = *(const short8v*)(arow + kk * 32);
#pragma unroll
                for (int u = 0; u < 3; ++u)
                    acc[u] = __builtin_amdgcn_mfma_f32_16x16x32_bf16(a, B[kk + u], acc[u], 0, 0, 0);
            }
            unsigned short uv[4];
#pragma unroll
            for (int e = 0; e < 4; ++e) {
                int o2 = ot * 16 + kg * 4 + e;
                float m = fmaxf(fmaxf(acc[0][e], acc[1][e]), acc[2][e]);
                uv[e] = bfb((o2 < 50) ? eluf(m * ws[F_S2 + o2] + ws[F_H2 + o2]) : 0.f);
            }
            uint2 pk = {(unsigned)uv[0] | ((unsigned)uv[1] << 16),
                        (unsigned)uv[2] | ((unsigned)uv[3] << 16)};
            *(uint2*)(p2 + (size_t)(tp * 128 + s0 + lo) * 64 + ot * 16 + kg * 4) = pk;
        }
    }
    gbar(bar, NBLK * 3);

    // ================= phase 3: L3 GEMM (50->100) ========================
    {
        const __hip_bfloat16* p2 = wsh + H_P2;
        const __hip_bfloat16* W = wsh + H_WA3;
        __hip_bfloat16* p3 = wsh + H_P3;
        for (int w = gw; w < 1472; w += NWAV) {      // 8 oti x 184 cols
            int oti = w / 184, cw = w - oti * 184;
            int tp = cw >> 3, s0 = (cw & 7) * 16;
            __hip_bfloat16* obase = p3 + (size_t)(tp * 128 + s0 + lo) * 128;
            if (oti == 7) {                          // zero-fill pad c 112..127
                uint2 z = {0, 0};
                *(uint2*)(obase + 112 + kg * 4) = z;
                continue;
            }
            int oz = oti >> 2, ot = oti & 3;
            const __hip_bfloat16* bbase = p2 + (size_t)(s0 + lo) * 64 + kg * 8;
            f32x4 acc[3];
#pragma unroll
            for (int u = 0; u < 3; ++u) acc[u] = (f32x4){0.f, 0.f, 0.f, 0.f};
#pragma unroll
            for (int cb = 0; cb < 2; ++cb) {
                short8v B[12];
#pragma unroll
                for (int v = 0; v < 12; ++v)
                    B[v] = *(const short8v*)(bbase + (size_t)(3 * tp + v) * 8192 + cb * 32);
                const __hip_bfloat16* arow =
                    W + (size_t)(oz * 64 + ot * 16 + lo) * 640 + cb * 32 + kg * 8;
#pragma unroll
                for (int kk = 0; kk < 10; ++kk) {
                    short8v a = *(const short8v*)(arow + kk * 64);
#pragma unroll
                    for (int u = 0; u < 3; ++u)
                        acc[u] = __builtin_amdgcn_mfma_f32_16x16x32_bf16(a, B[kk + u], acc[u], 0, 0, 0);
                }
            }
            unsigned short uv[4];
#pragma unroll
            for (int e = 0; e < 4; ++e) {
                int o2 = oz * 64 + ot * 16 + kg * 4 + e;
                float val = 0.f;
                if (o2 < 100) {
                    float m = fmaxf(fmaxf(acc[0][e], acc[1][e]), acc[2][e]);
                    val = eluf(m * ws[F_S3 + o2] + ws[F_H3 + o2]);
                }
                uv[e] = bfb(val);
            }
            uint2 pk = {(unsigned)uv[0] | ((unsigned)uv[1] << 16),
                        (unsigned)uv[2] | ((unsigned)uv[3] << 16)};
            *(uint2*)(obase + oz * 64 + ot * 16 + kg * 4) = pk;
        }
    }
    gbar(bar, NBLK * 4);

    // ================= phase 4: L4 GEMM (100->200), fp32 out =============
    {
        const __hip_bfloat16* p3 = wsh + H_P3;
        const __hip_bfloat16* W = wsh + H_WA4;
        float* p4 = ws + F_P4;
        for (int w = gw; w < 416; w += NWAV) {       // 13 ot x 32 cols
            int ot = w >> 5, ct = w & 31;
            int tp = ct >> 3, s0 = (ct & 7) * 16;
            const __hip_bfloat16* bbase = p3 + (size_t)(s0 + lo) * 128 + kg * 8;
            const __hip_bfloat16* arow0 = W + (size_t)(ot * 16 + lo) * 1280 + kg * 8;
            f32x4 acc[3];
#pragma unroll
            for (int u = 0; u < 3; ++u) acc[u] = (f32x4){0.f, 0.f, 0.f, 0.f};
#pragma unroll
            for (int cb = 0; cb < 4; ++cb) {
                short8v B[12];
#pragma unroll
                for (int v = 0; v < 12; ++v)
                    B[v] = *(const short8v*)(bbase + (size_t)(3 * tp + v) * 16384 + cb * 32);
                const __hip_bfloat16* arow = arow0 + cb * 32;
#pragma unroll
                for (int kk = 0; kk < 10; ++kk) {
                    short8v a = *(const short8v*)(arow + kk * 128);
#pragma unroll
                    for (int u = 0; u < 3; ++u)
                        acc[u] = __builtin_amdgcn_mfma_f32_16x16x32_bf16(a, B[kk + u], acc[u], 0, 0, 0);
                }
            }
#pragma unroll
            for (int e = 0; e < 4; ++e) {
                int o2 = ot * 16 + kg * 4 + e;
                if (o2 < 200) {
                    float m = fmaxf(fmaxf(acc[0][e], acc[1][e]), acc[2][e]);
                    p4[((size_t)(s0 + lo) * 200 + o2) * 4 + tp] =
                        eluf(m * ws[F_S4 + o2] + ws[F_H4 + o2]);
                }
            }
        }
    }
    gbar(bar, NBLK * 5);

    // ================= phase 5: fc + MoE heads (blocks 0..127) ===========
    if (blockIdx.x < 128) {
        const float* p4 = ws + F_P4;
        float* red = (float*)smem;                   // [4][128]
        float* fsf = (float*)(smem + 2048);          // [4]
        int b = blockIdx.x, j = tid;

        if (j < 128) {
            float pa[4] = {0.f, 0.f, 0.f, 0.f};
            for (int c = j; c < 200; c += 128) {
                const float* pp = p4 + ((size_t)b * 200 + c) * 4;
                float v0 = pp[0], v1 = pp[1], v2 = pp[2], v3 = pp[3];
#pragma unroll
                for (int o = 0; o < 4; ++o) {
                    const float* fw = fcw + (o * 200 + c) * 4;
                    pa[o] += fw[0] * v0 + fw[1] * v1 + fw[2] * v2 + fw[3] * v3;
                }
            }
#pragma unroll
            for (int o = 0; o < 4; ++o) red[o * 128 + j] = pa[o];
        }
        __syncthreads();
        for (int s = 64; s > 0; s >>= 1) {
            if (j < s) {
#pragma unroll
                for (int o = 0; o < 4; ++o) red[o * 128 + j] += red[o * 128 + j + s];
            }
            __syncthreads();
        }
        if (j < 4) fsf[j] = red[j * 128] + fcb[j];
        __syncthreads();

        int cid = cids[b];
        if (j < 128) {
            float hvv = hb1[cid * 128 + j];
#pragma unroll
            for (int f = 0; f < 4; ++f) hvv += fsf[f] * hW1[(cid * 4 + f) * 128 + j];
            hvv = fmaxf(hvv, 0.f);
#pragma unroll
            for (int o = 0; o < 4; ++o) red[o * 128 + j] = hvv * hW2[(cid * 128 + j) * 4 + o];
        }
        __syncthreads();
        for (int s = 64; s > 0; s >>= 1) {
            if (j < s) {
#pragma unroll
                for (int o = 0; o < 4; ++o) red[o * 128 + j] += red[o * 128 + j + s];
            }
            __syncthreads();
        }
        if (j < 4) out[b * 4 + j] = red[j * 128] + hb2[cid * 4 + j];
    }
}

// ---------------- launch ----------------
extern "C" void kernel_launch(void* const* d_in, const int* in_sizes, int n_in,
                              void* d_out, int out_size, void* d_ws, size_t ws_size,
                              hipStream_t stream) {
    (void)in_sizes; (void)n_in; (void)out_size; (void)ws_size;
    const float* x    = (const float*)d_in[0];
    const int*   cid  = (const int*)d_in[1];
    const float* ctw  = (const float*)d_in[2];
    const float* ctb  = (const float*)d_in[3];
    const float* csw  = (const float*)d_in[4];
    const float* g1 = (const float*)d_in[5],  *b1 = (const float*)d_in[6];
    const float* m1 = (const float*)d_in[7],  *v1 = (const float*)d_in[8];
    const float* w2 = (const float*)d_in[9];
    const float* g2 = (const float*)d_in[10], *b2 = (const float*)d_in[11];
    const float* m2 = (const float*)d_in[12], *v2 = (const float*)d_in[13];
    const float* w3 = (const float*)d_in[14];
    const float* g3 = (const float*)d_in[15], *b3 = (const float*)d_in[16];
    const float* m3 = (const float*)d_in[17], *v3 = (const float*)d_in[18];
    const float* w4 = (const float*)d_in[19];
    const float* g4 = (const float*)d_in[20], *b4 = (const float*)d_in[21];
    const float* m4 = (const float*)d_in[22], *v4 = (const float*)d_in[23];
    const float* fcw = (const float*)d_in[24], *fcb = (const float*)d_in[25];
    const float* hW1 = (const float*)d_in[26], *hb1 = (const float*)d_in[27];
    const float* hW2 = (const float*)d_in[28], *hb2 = (const float*)d_in[29];
    float* ws  = (float*)d_ws;
    float* out = (float*)d_out;

    // reset grid-barrier counter, then one persistent kernel
    hipMemsetAsync((char*)d_ws + F_BAR * 4, 0, 4, stream);
    k_mega<<<dim3(NBLK), dim3(256), 0, stream>>>(
        x, cid, ctw, ctb, csw,
        g1, b1, m1, v1, w2, g2, b2, m2, v2,
        w3, g3, b3, m3, v3, w4, g4, b4, m4, v4,
        fcw, fcb, hW1, hb1, hW2, hb2, ws, out);
}

// Round 9
// 270.981 us; speedup vs baseline: 2.3885x; 2.3885x over previous
//
#include <hip/hip_runtime.h>
#include <hip/hip_bf16.h>
#include <math.h>

typedef __attribute__((ext_vector_type(8))) short short8v;
typedef __attribute__((ext_vector_type(4))) float f32x4;

// ---------------- ws layout ----------------
// float region:
#define F_S1 0
#define F_H1 32
#define F_S2 64
#define F_H2 128
#define F_S3 192
#define F_H3 320
#define F_S4 448
#define F_H4 704
#define F_B1 960
#define F_BAR 1008       // barrier counter (memset to 0 each replay)
#define F_P4 1024        // 128*200*4 floats
#define F_END (1024 + 128*200*4)
// bf16 region:
#define H_BASE (F_END*2)
#define H_P1  H_BASE                    // [t=256][s=128][c=32] (t<247 written)
#define H_WA1 (H_P1 + 128*8192)         // 32*640
#define H_WA2 (H_WA1 + 32*640)          // 64*320
#define H_WA3 (H_WA2 + 64*320)          // 112*640
#define H_WA4 (H_WA3 + 112*640)         // 208*1280
#define H_P2  (H_WA4 + 208*1280)        // [t=79][s=128][c=64]
#define H_P3  (H_P2 + 79*128*64)        // [t=23][s=128][c=128]

#define N_WA1 (32*640)
#define N_WA2 (64*320)
#define N_WA3 (112*640)
#define N_WA4 (208*1280)
#define N_WTOT (N_WA1 + N_WA2 + N_WA3 + N_WA4)

#define NBLK 512
#define NTHR 131072      // NBLK*256
#define NWAV 2048        // NBLK*4

__device__ __forceinline__ float eluf(float v) {
    return v > 0.f ? v : (expf(v) - 1.f);
}
__device__ __forceinline__ float ldh(const __hip_bfloat16* p) { return __bfloat162float(*p); }
__device__ __forceinline__ unsigned short bfb(float v) {
    __hip_bfloat16 h = __float2bfloat16(v);
    return reinterpret_cast<unsigned short&>(h);
}
__device__ __forceinline__ void ld4f(const float* p, float* v) {
    float2 a = *(const float2*)p, c = *(const float2*)(p + 2);
    v[0] = a.x; v[1] = a.y; v[2] = c.x; v[3] = c.y;
}

// device-scope grid barrier, v2: RELAXED spin (no cache inv per poll),
// single RELEASE on arrival + single ACQUIRE on exit.
__device__ __forceinline__ void gbar(unsigned* bar, unsigned target) {
    __syncthreads();                 // all waves drain vmem before arrival
    if (threadIdx.x == 0) {
        __hip_atomic_fetch_add(bar, 1u, __ATOMIC_RELEASE, __HIP_MEMORY_SCOPE_AGENT);
        while (__hip_atomic_load(bar, __ATOMIC_RELAXED, __HIP_MEMORY_SCOPE_AGENT) < target)
            __builtin_amdgcn_s_sleep(8);
        (void)__hip_atomic_load(bar, __ATOMIC_ACQUIRE, __HIP_MEMORY_SCOPE_AGENT);
    }
    __syncthreads();
}

// ---------------- the single persistent kernel ----------------
__global__ __launch_bounds__(256, 2) void k_mega(
    const float* __restrict__ x, const int* __restrict__ cids,
    const float* __restrict__ ct_w, const float* __restrict__ ct_b,
    const float* __restrict__ cs_w,
    const float* __restrict__ g1, const float* __restrict__ b1,
    const float* __restrict__ m1, const float* __restrict__ v1,
    const float* __restrict__ w2,
    const float* __restrict__ g2, const float* __restrict__ b2,
    const float* __restrict__ m2, const float* __restrict__ v2,
    const float* __restrict__ w3,
    const float* __restrict__ g3, const float* __restrict__ b3,
    const float* __restrict__ m3, const float* __restrict__ v3,
    const float* __restrict__ w4,
    const float* __restrict__ g4, const float* __restrict__ b4,
    const float* __restrict__ m4, const float* __restrict__ v4,
    const float* __restrict__ fcw, const float* __restrict__ fcb,
    const float* __restrict__ hW1, const float* __restrict__ hb1,
    const float* __restrict__ hW2, const float* __restrict__ hb2,
    float* __restrict__ ws, float* __restrict__ out) {
    __hip_bfloat16* wsh = (__hip_bfloat16*)ws;
    unsigned* bar = (unsigned*)(ws + F_BAR);
    int tid = threadIdx.x;
    int gtid = blockIdx.x * 256 + tid;
    int lane = tid & 63, wid = tid >> 6;
    int lo = lane & 15, kg = lane >> 4;
    int gw = blockIdx.x * 4 + wid;

    // LDS: conv1 phase uses xb(26624B)+eb(12288B); heads phase reuses front.
    __shared__ __align__(16) unsigned char smem[26624 + 12288];
    __hip_bfloat16* xb = (__hip_bfloat16*)smem;            // [208][64]
    __hip_bfloat16* eb = (__hip_bfloat16*)(smem + 26624);  // [32][192]

    // ================= phase 0: weight prep + BN affines =================
    for (int t = gtid; t < N_WTOT + 960; t += NTHR) {
        if (t < N_WA1) {
            int o = t / 640, kv = t - o * 640, kk = kv / 64, c = kv - kk * 64;
            float s = 0.f;
            if (o < 25)
                for (int i = 0; i < 25; ++i)
                    s += cs_w[(o * 25 + i) * 64 + c] * ct_w[i * 10 + kk];
            wsh[H_WA1 + t] = __float2bfloat16(s);
        } else if (t < N_WA1 + N_WA2) {
            int u = t - N_WA1;
            int o = u / 320, kv = u - o * 320, kk = kv / 32, c = kv - kk * 32;
            float s = (o < 50 && c < 25) ? w2[(o * 25 + c) * 10 + kk] : 0.f;
            wsh[H_WA2 + u] = __float2bfloat16(s);
        } else if (t < N_WA1 + N_WA2 + N_WA3) {
            int u = t - N_WA1 - N_WA2;
            int o = u / 640, kv = u - o * 640, kk = kv / 64, c = kv - kk * 64;
            float s = (o < 100 && c < 50) ? w3[(o * 50 + c) * 10 + kk] : 0.f;
            wsh[H_WA3 + u] = __float2bfloat16(s);
        } else if (t < N_WTOT) {
            int u = t - N_WA1 - N_WA2 - N_WA3;
            int o = u / 1280, kv = u - o * 1280, kk = kv / 128, c = kv - kk * 128;
            float s = (o < 200 && c < 100) ? w4[(o * 100 + c) * 10 + kk] : 0.f;
            wsh[H_WA4 + u] = __float2bfloat16(s);
        } else {
            int j = t - N_WTOT;
            if (j < 25) {
                float sc = g1[j] / sqrtf(v1[j] + 1e-5f);
                ws[F_S1 + j] = sc; ws[F_H1 + j] = b1[j] - m1[j] * sc;
            } else if (j >= 32 && j < 82) {
                int ch = j - 32;
                float sc = g2[ch] / sqrtf(v2[ch] + 1e-5f);
                ws[F_S2 + ch] = sc; ws[F_H2 + ch] = b2[ch] - m2[ch] * sc;
            } else if (j >= 96 && j < 196) {
                int ch = j - 96;
                float sc = g3[ch] / sqrtf(v3[ch] + 1e-5f);
                ws[F_S3 + ch] = sc; ws[F_H3 + ch] = b3[ch] - m3[ch] * sc;
            } else if (j >= 224 && j < 424) {
                int ch = j - 224;
                float sc = g4[ch] / sqrtf(v4[ch] + 1e-5f);
                ws[F_S4 + ch] = sc; ws[F_H4 + ch] = b4[ch] - m4[ch] * sc;
            } else if (j >= 448 && j < 473) {
                int o = j - 448;
                float s = 0.f;
                for (int i = 0; i < 25; ++i) {
                    float cs = 0.f;
                    for (int c = 0; c < 64; ++c) cs += cs_w[(o * 25 + i) * 64 + c];
                    s += cs * ct_b[i];
                }
                ws[F_B1 + o] = s;
            }
        }
    }
    gbar(bar, NBLK * 1);

    // ================= phase 1: conv1+BN+ELU+pool (1 tile/block) =========
    {
        int tile = blockIdx.x;            // 512 tiles = 4 t-tiles x 128 samples
        int b = tile >> 2, bx = tile & 3;
        int tp0 = 62 * bx;
        int PTb = min(62, 247 - tp0);     // 62,62,62,61
        int t0 = 186 * bx;

        for (int f = tid; f < 64 * 52; f += 256) {
            int c = f / 52, j = f - c * 52;
            int t = t0 + 4 * j;
            const float* src = x + ((size_t)b * 64 + c) * 750 + t;
            float v[4];
            if (t + 3 < 750) {
                ld4f(src, v);
            } else {
#pragma unroll
                for (int e = 0; e < 4; ++e) v[e] = (t + e < 750) ? src[e] : 0.f;
            }
#pragma unroll
            for (int e = 0; e < 4; ++e) {
                int r = 4 * j + e;
                xb[r * 64 + (c ^ (8 * (r & 7)))] = __float2bfloat16(v[e]);
            }
        }
        __syncthreads();

        int ot = wid >> 1, ctg = wid & 1;            // 2 ot x 2 ct-groups
        const short8v* Ap = (const short8v*)(wsh + H_WA1 + (size_t)(ot * 16 + lo) * 640);
        f32x4 acc[6];
#pragma unroll
        for (int q = 0; q < 6; ++q) acc[q] = (f32x4){0.f, 0.f, 0.f, 0.f};
#pragma unroll 1
        for (int sb = 0; sb < 20; sb += 10) {
            short8v af[10];
#pragma unroll
            for (int u = 0; u < 10; ++u) af[u] = Ap[(sb + u) * 4 + kg];
#pragma unroll
            for (int u = 0; u < 10; ++u) {
                int s = sb + u;
                int kk = s >> 1, cb = s & 1;
#pragma unroll
                for (int q = 0; q < 6; ++q) {
                    int r = (ctg * 6 + q) * 16 + lo + kk;
                    int cs = (cb * 32 + kg * 8) ^ (8 * (r & 7));
                    short8v bf = *(const short8v*)&xb[r * 64 + cs];
                    acc[q] = __builtin_amdgcn_mfma_f32_16x16x32_bf16(af[u], bf, acc[q], 0, 0, 0);
                }
            }
        }
#pragma unroll
        for (int q = 0; q < 6; ++q) {
            int tloc = (ctg * 6 + q) * 16 + lo;
#pragma unroll
            for (int e = 0; e < 4; ++e) {
                int o2 = ot * 16 + kg * 4 + e;       // < 32
                float a = acc[q][e] + ws[F_B1 + o2];
                eb[o2 * 192 + tloc] = __float2bfloat16(eluf(a * ws[F_S1 + o2] + ws[F_H1 + o2]));
            }
        }
        __syncthreads();

        // coalesced epilogue: og fastest -> 8 lanes cover one 64B line per tp
        __hip_bfloat16* p1g = wsh + H_P1;
        for (int i = tid; i < 62 * 8; i += 256) {
            int pl = i >> 3, og = i & 7;
            if (pl < PTb) {
                int tp = tp0 + pl;
                unsigned short uv[4];
#pragma unroll
                for (int j = 0; j < 4; ++j) {
                    int o = og * 4 + j;
                    float v = 0.f;
                    if (o < 25) {
                        const __hip_bfloat16* ep = eb + o * 192 + 3 * pl;
                        v = fmaxf(fmaxf(ldh(ep), ldh(ep + 1)), ldh(ep + 2));
                    }
                    uv[j] = bfb(v);
                }
                uint2 pk = {(unsigned)uv[0] | ((unsigned)uv[1] << 16),
                            (unsigned)uv[2] | ((unsigned)uv[3] << 16)};
                *(uint2*)(p1g + (size_t)tp * 4096 + b * 32 + og * 4) = pk;
            }
        }
    }
    gbar(bar, NBLK * 2);

    // ================= phase 2: L2 GEMM (25->50), B reused over 2 ot =====
    {
        const __hip_bfloat16* p1 = wsh + H_P1;
        const __hip_bfloat16* W = wsh + H_WA2;
        __hip_bfloat16* p2 = wsh + H_P2;
        for (int w = gw; w < 1264; w += NWAV) {      // 632 cols x 2 ot-pairs
            int otp = w & 1, cw = w >> 1;
            int tp = cw >> 3, s0 = (cw & 7) * 16;
            const __hip_bfloat16* bbase = p1 + (size_t)(s0 + lo) * 32 + kg * 8;
            short8v B[12];
#pragma unroll
            for (int v = 0; v < 12; ++v)
                B[v] = *(const short8v*)(bbase + (size_t)(3 * tp + v) * 4096);
#pragma unroll
            for (int oi = 0; oi < 2; ++oi) {
                int ot = otp * 2 + oi;
                f32x4 acc[3];
#pragma unroll
                for (int u = 0; u < 3; ++u) acc[u] = (f32x4){0.f, 0.f, 0.f, 0.f};
                const __hip_bfloat16* arow = W + (size_t)(ot * 16 + lo) * 320 + kg * 8;
#pragma unroll
                for (int kk = 0; kk < 10; ++kk) {
                    short8v a = *(const short8v*)(arow + kk * 32);
#pragma unroll
                    for (int u = 0; u < 3; ++u)
                        acc[u] = __builtin_amdgcn_mfma_f32_16x16x32_bf16(a, B[kk + u], acc[u], 0, 0, 0);
                }
                unsigned short uv[4];
#pragma unroll
                for (int e = 0; e < 4; ++e) {
                    int o2 = ot * 16 + kg * 4 + e;
                    float m = fmaxf(fmaxf(acc[0][e], acc[1][e]), acc[2][e]);
                    uv[e] = bfb((o2 < 50) ? eluf(m * ws[F_S2 + o2] + ws[F_H2 + o2]) : 0.f);
                }
                uint2 pk = {(unsigned)uv[0] | ((unsigned)uv[1] << 16),
                            (unsigned)uv[2] | ((unsigned)uv[3] << 16)};
                *(uint2*)(p2 + (size_t)(tp * 128 + s0 + lo) * 64 + ot * 16 + kg * 4) = pk;
            }
        }
    }
    gbar(bar, NBLK * 3);

    // ================= phase 3: L3 GEMM (50->100) ========================
    {
        const __hip_bfloat16* p2 = wsh + H_P2;
        const __hip_bfloat16* W = wsh + H_WA3;
        __hip_bfloat16* p3 = wsh + H_P3;
        for (int w = gw; w < 1472; w += NWAV) {      // 8 oti x 184 cols
            int oti = w / 184, cw = w - oti * 184;
            int tp = cw >> 3, s0 = (cw & 7) * 16;
            __hip_bfloat16* obase = p3 + (size_t)(tp * 128 + s0 + lo) * 128;
            if (oti == 7) {                          // zero-fill pad c 112..127
                uint2 z = {0, 0};
                *(uint2*)(obase + 112 + kg * 4) = z;
                continue;
            }
            int oz = oti >> 2, ot = oti & 3;
            const __hip_bfloat16* bbase = p2 + (size_t)(s0 + lo) * 64 + kg * 8;
            f32x4 acc[3];
#pragma unroll
            for (int u = 0; u < 3; ++u) acc[u] = (f32x4){0.f, 0.f, 0.f, 0.f};
#pragma unroll
            for (int cb = 0; cb < 2; ++cb) {
                short8v B[12];
#pragma unroll
                for (int v = 0; v < 12; ++v)
                    B[v] = *(const short8v*)(bbase + (size_t)(3 * tp + v) * 8192 + cb * 32);
                const __hip_bfloat16* arow =
                    W + (size_t)(oz * 64 + ot * 16 + lo) * 640 + cb * 32 + kg * 8;
#pragma unroll
                for (int kk = 0; kk < 10; ++kk) {
                    short8v a = *(const short8v*)(arow + kk * 64);
#pragma unroll
                    for (int u = 0; u < 3; ++u)
                        acc[u] = __builtin_amdgcn_mfma_f32_16x16x32_bf16(a, B[kk + u], acc[u], 0, 0, 0);
                }
            }
            unsigned short uv[4];
#pragma unroll
            for (int e = 0; e < 4; ++e) {
                int o2 = oz * 64 + ot * 16 + kg * 4 + e;
                float val = 0.f;
                if (o2 < 100) {
                    float m = fmaxf(fmaxf(acc[0][e], acc[1][e]), acc[2][e]);
                    val = eluf(m * ws[F_S3 + o2] + ws[F_H3 + o2]);
                }
                uv[e] = bfb(val);
            }
            uint2 pk = {(unsigned)uv[0] | ((unsigned)uv[1] << 16),
                        (unsigned)uv[2] | ((unsigned)uv[3] << 16)};
            *(uint2*)(obase + oz * 64 + ot * 16 + kg * 4) = pk;
        }
    }
    gbar(bar, NBLK * 4);

    // ================= phase 4: L4 GEMM (100->200), fp32 out =============
    {
        const __hip_bfloat16* p3 = wsh + H_P3;
        const __hip_bfloat16* W = wsh + H_WA4;
        float* p4 = ws + F_P4;
        for (int w = gw; w < 416; w += NWAV) {       // 13 ot x 32 cols
            int ot = w >> 5, ct = w & 31;
            int tp = ct >> 3, s0 = (ct & 7) * 16;
            const __hip_bfloat16* bbase = p3 + (size_t)(s0 + lo) * 128 + kg * 8;
            const __hip_bfloat16* arow0 = W + (size_t)(ot * 16 + lo) * 1280 + kg * 8;
            f32x4 acc[3];
#pragma unroll
            for (int u = 0; u < 3; ++u) acc[u] = (f32x4){0.f, 0.f, 0.f, 0.f};
#pragma unroll
            for (int cb = 0; cb < 4; ++cb) {
                short8v B[12];
#pragma unroll
                for (int v = 0; v < 12; ++v)
                    B[v] = *(const short8v*)(bbase + (size_t)(3 * tp + v) * 16384 + cb * 32);
                const __hip_bfloat16* arow = arow0 + cb * 32;
#pragma unroll
                for (int kk = 0; kk < 10; ++kk) {
                    short8v a = *(const short8v*)(arow + kk * 128);
#pragma unroll
                    for (int u = 0; u < 3; ++u)
                        acc[u] = __builtin_amdgcn_mfma_f32_16x16x32_bf16(a, B[kk + u], acc[u], 0, 0, 0);
                }
            }
#pragma unroll
            for (int e = 0; e < 4; ++e) {
                int o2 = ot * 16 + kg * 4 + e;
                if (o2 < 200) {
                    float m = fmaxf(fmaxf(acc[0][e], acc[1][e]), acc[2][e]);
                    p4[((size_t)(s0 + lo) * 200 + o2) * 4 + tp] =
                        eluf(m * ws[F_S4 + o2] + ws[F_H4 + o2]);
                }
            }
        }
    }
    gbar(bar, NBLK * 5);

    // ================= phase 5: fc + MoE heads (blocks 0..127) ===========
    if (blockIdx.x < 128) {
        const float* p4 = ws + F_P4;
        float* red = (float*)smem;                   // [4][128]
        float* fsf = (float*)(smem + 2048);          // [4]
        int b = blockIdx.x, j = tid;

        if (j < 128) {
            float pa[4] = {0.f, 0.f, 0.f, 0.f};
            for (int c = j; c < 200; c += 128) {
                const float* pp = p4 + ((size_t)b * 200 + c) * 4;
                float v0 = pp[0], v1 = pp[1], v2 = pp[2], v3 = pp[3];
#pragma unroll
                for (int o = 0; o < 4; ++o) {
                    const float* fw = fcw + (o * 200 + c) * 4;
                    pa[o] += fw[0] * v0 + fw[1] * v1 + fw[2] * v2 + fw[3] * v3;
                }
            }
#pragma unroll
            for (int o = 0; o < 4; ++o) red[o * 128 + j] = pa[o];
        }
        __syncthreads();
        for (int s = 64; s > 0; s >>= 1) {
            if (j < s) {
#pragma unroll
                for (int o = 0; o < 4; ++o) red[o * 128 + j] += red[o * 128 + j + s];
            }
            __syncthreads();
        }
        if (j < 4) fsf[j] = red[j * 128] + fcb[j];
        __syncthreads();

        int cid = cids[b];
        if (j < 128) {
            float hvv = hb1[cid * 128 + j];
#pragma unroll
            for (int f = 0; f < 4; ++f) hvv += fsf[f] * hW1[(cid * 4 + f) * 128 + j];
            hvv = fmaxf(hvv, 0.f);
#pragma unroll
            for (int o = 0; o < 4; ++o) red[o * 128 + j] = hvv * hW2[(cid * 128 + j) * 4 + o];
        }
        __syncthreads();
        for (int s = 64; s > 0; s >>= 1) {
            if (j < s) {
#pragma unroll
                for (int o = 0; o < 4; ++o) red[o * 128 + j] += red[o * 128 + j + s];
            }
            __syncthreads();
        }
        if (j < 4) out[b * 4 + j] = red[j * 128] + hb2[cid * 4 + j];
    }
}

// ---------------- launch ----------------
extern "C" void kernel_launch(void* const* d_in, const int* in_sizes, int n_in,
                              void* d_out, int out_size, void* d_ws, size_t ws_size,
                              hipStream_t stream) {
    (void)in_sizes; (void)n_in; (void)out_size; (void)ws_size;
    const float* x    = (const float*)d_in[0];
    const int*   cid  = (const int*)d_in[1];
    const float* ctw  = (const float*)d_in[2];
    const float* ctb  = (const float*)d_in[3];
    const float* csw  = (const float*)d_in[4];
    const float* g1 = (const float*)d_in[5],  *b1 = (const float*)d_in[6];
    const float* m1 = (const float*)d_in[7],  *v1 = (const float*)d_in[8];
    const float* w2 = (const float*)d_in[9];
    const float* g2 = (const float*)d_in[10], *b2 = (const float*)d_in[11];
    const float* m2 = (const float*)d_in[12], *v2 = (const float*)d_in[13];
    const float* w3 = (const float*)d_in[14];
    const float* g3 = (const float*)d_in[15], *b3 = (const float*)d_in[16];
    const float* m3 = (const float*)d_in[17], *v3 = (const float*)d_in[18];
    const float* w4 = (const float*)d_in[19];
    const float* g4 = (const float*)d_in[20], *b4 = (const float*)d_in[21];
    const float* m4 = (const float*)d_in[22], *v4 = (const float*)d_in[23];
    const float* fcw = (const float*)d_in[24], *fcb = (const float*)d_in[25];
    const float* hW1 = (const float*)d_in[26], *hb1 = (const float*)d_in[27];
    const float* hW2 = (const float*)d_in[28], *hb2 = (const float*)d_in[29];
    float* ws  = (float*)d_ws;
    float* out = (float*)d_out;

    // reset grid-barrier counter, then one persistent kernel
    hipMemsetAsync((char*)d_ws + F_BAR * 4, 0, 4, stream);
    k_mega<<<dim3(NBLK), dim3(256), 0, stream>>>(
        x, cid, ctw, ctb, csw,
        g1, b1, m1, v1, w2, g2, b2, m2, v2,
        w3, g3, b3, m3, v3, w4, g4, b4, m4, v4,
        fcw, fcb, hW1, hb1, hW2, hb2, ws, out);
}

// Round 10
// 151.664 us; speedup vs baseline: 4.2675x; 1.7867x over previous
//
#include <hip/hip_runtime.h>
#include <hip/hip_bf16.h>
#include <math.h>

typedef __attribute__((ext_vector_type(8))) short short8v;
typedef __attribute__((ext_vector_type(4))) float f32x4;

// ---------------- ws layout ----------------
// float region:
#define F_S2 64
#define F_H2 128
#define F_S3 192
#define F_H3 320
#define F_S4 448
#define F_H4 704
#define F_BAR 1008       // gemm4 completion counter (reset by k_front each call)
#define F_P4 1024        // 128*200*4 floats
#define F_END (1024 + 128*200*4)
// bf16 region:
#define H_BASE (F_END*2)
#define H_P1  H_BASE                    // [t=256][s=128][c=32] (t<247 written)
#define H_WA2 (H_P1 + 128*8192)         // 64*320   (o, kk*32+c)
#define H_WA3 (H_WA2 + 64*320)          // 112*640  (o, kk*64+c)
#define H_WA4 (H_WA3 + 112*640)         // 208*1280 (o, kk*128+c)
#define H_P2  (H_WA4 + 208*1280)        // [t=79][s=128][c=64]
#define H_P3  (H_P2 + 79*128*64)        // [t=23][s=128][c=128]

#define N_WA2 (64*320)
#define N_WA3 (112*640)
#define N_WA4 (208*1280)
#define N234  (N_WA2 + N_WA3 + N_WA4)   // 358400

#define CONV_BLOCKS 768                 // 6 t-tiles x 128 samples
#define CVT_BLOCKS  1402                // ceil((N234+392)/256)

__device__ __forceinline__ float eluf(float v) {
    return v > 0.f ? v : (expf(v) - 1.f);
}
__device__ __forceinline__ float ldh(const __hip_bfloat16* p) { return __bfloat162float(*p); }
__device__ __forceinline__ unsigned short bfb(float v) {
    __hip_bfloat16 h = __float2bfloat16(v);
    return reinterpret_cast<unsigned short&>(h);
}
__device__ __forceinline__ void ld4f(const float* p, float* v) {
    float2 a = *(const float2*)p, c = *(const float2*)(p + 2);
    v[0] = a.x; v[1] = a.y; v[2] = c.x; v[3] = c.y;
}

// ---------------- K1: conv1 (fused ct*cs) + BN1 + ELU + pool3,  ----------------
// plus (blocks >= 768) WA2/3/4 bf16 conversion + BN2-4 affines + counter reset.
__global__ __launch_bounds__(256) void k_front(
    const float* __restrict__ x,
    const float* __restrict__ ct_w, const float* __restrict__ ct_b,
    const float* __restrict__ cs_w,
    const float* __restrict__ g1, const float* __restrict__ b1,
    const float* __restrict__ m1, const float* __restrict__ v1,
    const float* __restrict__ w2,
    const float* __restrict__ g2, const float* __restrict__ b2,
    const float* __restrict__ m2, const float* __restrict__ v2,
    const float* __restrict__ w3,
    const float* __restrict__ g3, const float* __restrict__ b3,
    const float* __restrict__ m3, const float* __restrict__ v3,
    const float* __restrict__ w4,
    const float* __restrict__ g4, const float* __restrict__ b4,
    const float* __restrict__ m4, const float* __restrict__ v4,
    float* __restrict__ ws) {
    __hip_bfloat16* wsh = (__hip_bfloat16*)ws;
    int bx = blockIdx.x, tid = threadIdx.x;

    if (bx >= CONV_BLOCKS) {
        // ------- conversion / affine blocks (no LDS use, exit fast) -------
        if (bx == CONV_BLOCKS && tid == 0) {
            unsigned* cnt = (unsigned*)(ws + F_BAR);
            __hip_atomic_store(cnt, 0u, __ATOMIC_RELAXED, __HIP_MEMORY_SCOPE_AGENT);
        }
        int u = (bx - CONV_BLOCKS) * 256 + tid;
        if (u < N_WA2) {
            int o = u / 320, kv = u - o * 320, kk = kv / 32, c = kv - kk * 32;
            float s = (o < 50 && c < 25) ? w2[(o * 25 + c) * 10 + kk] : 0.f;
            wsh[H_WA2 + u] = __float2bfloat16(s);
        } else if (u < N_WA2 + N_WA3) {
            int v = u - N_WA2;
            int o = v / 640, kv = v - o * 640, kk = kv / 64, c = kv - kk * 64;
            float s = (o < 100 && c < 50) ? w3[(o * 50 + c) * 10 + kk] : 0.f;
            wsh[H_WA3 + v] = __float2bfloat16(s);
        } else if (u < N234) {
            int v = u - N_WA2 - N_WA3;
            int o = v / 1280, kv = v - o * 1280, kk = kv / 128, c = kv - kk * 128;
            float s = (o < 200 && c < 100) ? w4[(o * 100 + c) * 10 + kk] : 0.f;
            wsh[H_WA4 + v] = __float2bfloat16(s);
        } else {
            int j = u - N234;
            if (j < 50) {
                float sc = g2[j] / sqrtf(v2[j] + 1e-5f);
                ws[F_S2 + j] = sc; ws[F_H2 + j] = b2[j] - m2[j] * sc;
            } else if (j >= 64 && j < 164) {
                int ch = j - 64;
                float sc = g3[ch] / sqrtf(v3[ch] + 1e-5f);
                ws[F_S3 + ch] = sc; ws[F_H3 + ch] = b3[ch] - m3[ch] * sc;
            } else if (j >= 192 && j < 392) {
                int ch = j - 192;
                float sc = g4[ch] / sqrtf(v4[ch] + 1e-5f);
                ws[F_S4 + ch] = sc; ws[F_H4 + ch] = b4[ch] - m4[ch] * sc;
            }
        }
        return;
    }

    // ------------------- conv1 tile block -------------------
    int b = bx / 6, sub = bx % 6;
    int tp0 = sub * 42;
    int PTb = min(42, 247 - tp0);
    int t0 = 126 * sub;
    int lane = tid & 63, wid = tid >> 6;
    int lo = lane & 15, kg = lane >> 4;

    __shared__ __align__(16) __hip_bfloat16 wa1[32 * 640];   // 40960 B, swizzled
    __shared__ __align__(16) __hip_bfloat16 xb[144 * 64];    // 18432 B; eb aliases
    __shared__ float ctl[250];
    __shared__ float ctbl[25];
    __shared__ float s1l[32], h1l[32], b1l[32];
    __hip_bfloat16* eb = xb;                                 // [32][128] after MFMA

    // phase A: stage small tables, zero pads
    if (tid < 250) ctl[tid] = ct_w[tid];
    if (tid >= 256 - 25) ctbl[tid - (256 - 25)] = ct_b[tid - (256 - 25)];
    if (tid < 32) {
        b1l[tid] = 0.f;
        float sc = 0.f, hh = 0.f;
        if (tid < 25) {
            sc = g1[tid] / sqrtf(v1[tid] + 1e-5f);
            hh = b1[tid] - m1[tid] * sc;
        }
        s1l[tid] = sc; h1l[tid] = hh;
    }
    for (int e = tid; e < 7 * 640; e += 256)                 // rows 25..31 zero
        wa1[25 * 640 + e] = __float2bfloat16(0.f);
    __syncthreads();

    // phase B: WA1 = cs_w @ ct_w into LDS (each cs element read once) + xb stage
    for (int p = tid; p < 1600; p += 256) {
        int o = p >> 6, c = p & 63;
        float cw[25];
#pragma unroll
        for (int i = 0; i < 25; ++i) cw[i] = cs_w[(o * 25 + i) * 64 + c];
        float tb = 0.f;
#pragma unroll
        for (int i = 0; i < 25; ++i) tb += cw[i] * ctbl[i];
        atomicAdd(&b1l[o], tb);
        int omask = 8 * (o & 7);
#pragma unroll
        for (int kk = 0; kk < 10; ++kk) {
            float s = 0.f;
#pragma unroll
            for (int i = 0; i < 25; ++i) s += cw[i] * ctl[i * 10 + kk];
            wa1[o * 640 + ((kk * 64 + c) ^ omask)] = __float2bfloat16(s);
        }
    }
    for (int f = tid; f < 64 * 36; f += 256) {
        int c = f / 36, j = f - c * 36;
        int t = t0 + 4 * j;
        const float* src = x + ((size_t)b * 64 + c) * 750 + t;
        float v[4];
        if (t + 3 < 750) {
            ld4f(src, v);
        } else {
#pragma unroll
            for (int e = 0; e < 4; ++e) v[e] = (t + e < 750) ? src[e] : 0.f;
        }
#pragma unroll
        for (int e = 0; e < 4; ++e) {
            int r = 4 * j + e;
            xb[r * 64 + (c ^ (8 * (r & 7)))] = __float2bfloat16(v[e]);
        }
    }
    __syncthreads();

    // MFMA: 4 waves -> (ot, ctg); A-frags from LDS wa1 (swizzled by row&7)
    int ot = wid >> 1, ctg = wid & 1;
    const __hip_bfloat16* Arow = wa1 + (ot * 16 + lo) * 640;
    int amask = 8 * (lo & 7);
    f32x4 acc[4];
#pragma unroll
    for (int q = 0; q < 4; ++q) acc[q] = (f32x4){0.f, 0.f, 0.f, 0.f};
#pragma unroll 1
    for (int sb = 0; sb < 20; sb += 10) {
        short8v af[10];
#pragma unroll
        for (int u = 0; u < 10; ++u)
            af[u] = *(const short8v*)&Arow[(((sb + u) * 32 + kg * 8)) ^ amask];
#pragma unroll
        for (int u = 0; u < 10; ++u) {
            int s = sb + u;
            int kk = s >> 1, cb = s & 1;
#pragma unroll
            for (int q = 0; q < 4; ++q) {
                int r = (ctg * 4 + q) * 16 + lo + kk;
                int cs = (cb * 32 + kg * 8) ^ (8 * (r & 7));
                short8v bf = *(const short8v*)&xb[r * 64 + cs];
                acc[q] = __builtin_amdgcn_mfma_f32_16x16x32_bf16(af[u], bf, acc[q], 0, 0, 0);
            }
        }
    }
    __syncthreads();                 // all xb reads done before eb (alias) writes

#pragma unroll
    for (int q = 0; q < 4; ++q) {
        int tloc = (ctg * 4 + q) * 16 + lo;
#pragma unroll
        for (int e = 0; e < 4; ++e) {
            int o2 = ot * 16 + kg * 4 + e;      // < 32
            float a = acc[q][e] + b1l[o2];
            eb[o2 * 128 + tloc] = __float2bfloat16(eluf(a * s1l[o2] + h1l[o2]));
        }
    }
    __syncthreads();

    // pool + store [t][s][32] (og fastest -> coalesced 64B lines)
    __hip_bfloat16* p1g = wsh + H_P1;
    for (int i = tid; i < 42 * 8; i += 256) {
        int pl = i >> 3, og = i & 7;
        if (pl < PTb) {
            int tp = tp0 + pl;
            unsigned short uv[4];
#pragma unroll
            for (int j = 0; j < 4; ++j) {
                int o = og * 4 + j;
                float v = 0.f;
                if (o < 25) {
                    const __hip_bfloat16* ep = eb + o * 128 + 3 * pl;
                    v = fmaxf(fmaxf(ldh(ep), ldh(ep + 1)), ldh(ep + 2));
                }
                uv[j] = bfb(v);
            }
            uint2 pk = {(unsigned)uv[0] | ((unsigned)uv[1] << 16),
                        (unsigned)uv[2] | ((unsigned)uv[3] << 16)};
            *(uint2*)(p1g + (size_t)tp * 4096 + b * 32 + og * 4) = pk;
        }
    }
}

// ---------------- K2: L2 batched GEMM (25->50), B reused over 2 ot ----------------
__global__ __launch_bounds__(256) void k_gemm2(float* __restrict__ ws) {
    __hip_bfloat16* wsh = (__hip_bfloat16*)ws;
    const __hip_bfloat16* p1 = wsh + H_P1;
    const __hip_bfloat16* W = wsh + H_WA2;
    __hip_bfloat16* p2 = wsh + H_P2;
    int w = blockIdx.x * 4 + (threadIdx.x >> 6);          // < 1264
    int lane = threadIdx.x & 63, lo = lane & 15, kg = lane >> 4;
    int otp = w & 1, cw = w >> 1;
    int tp = cw >> 3, s0 = (cw & 7) * 16;

    const __hip_bfloat16* bbase = p1 + (size_t)(s0 + lo) * 32 + kg * 8;
    short8v B[12];
#pragma unroll
    for (int v = 0; v < 12; ++v)
        B[v] = *(const short8v*)(bbase + (size_t)(3 * tp + v) * 4096);
#pragma unroll
    for (int oi = 0; oi < 2; ++oi) {
        int ot = otp * 2 + oi;
        f32x4 acc[3];
#pragma unroll
        for (int u = 0; u < 3; ++u) acc[u] = (f32x4){0.f, 0.f, 0.f, 0.f};
        const __hip_bfloat16* arow = W + (size_t)(ot * 16 + lo) * 320 + kg * 8;
#pragma unroll
        for (int kk = 0; kk < 10; ++kk) {
            short8v a = *(const short8v*)(arow + kk * 32);
#pragma unroll
            for (int u = 0; u < 3; ++u)
                acc[u] = __builtin_amdgcn_mfma_f32_16x16x32_bf16(a, B[kk + u], acc[u], 0, 0, 0);
        }
        unsigned short uv[4];
#pragma unroll
        for (int e = 0; e < 4; ++e) {
            int o2 = ot * 16 + kg * 4 + e;
            float m = fmaxf(fmaxf(acc[0][e], acc[1][e]), acc[2][e]);
            uv[e] = bfb((o2 < 50) ? eluf(m * ws[F_S2 + o2] + ws[F_H2 + o2]) : 0.f);
        }
        uint2 pk = {(unsigned)uv[0] | ((unsigned)uv[1] << 16),
                    (unsigned)uv[2] | ((unsigned)uv[3] << 16)};
        *(uint2*)(p2 + (size_t)(tp * 128 + s0 + lo) * 64 + ot * 16 + kg * 4) = pk;
    }
}

// ---------------- K3: L3 batched GEMM (50->100) ----------------
__global__ __launch_bounds__(256) void k_gemm3(float* __restrict__ ws) {
    __hip_bfloat16* wsh = (__hip_bfloat16*)ws;
    const __hip_bfloat16* p2 = wsh + H_P2;
    const __hip_bfloat16* W = wsh + H_WA3;
    __hip_bfloat16* p3 = wsh + H_P3;
    int w = blockIdx.x * 4 + (threadIdx.x >> 6);          // < 368
    int lane = threadIdx.x & 63, lo = lane & 15, kg = lane >> 4;
    int col = w >> 1, oz = w & 1;
    int tp = col >> 3, s0 = (col & 7) * 16;

    const __hip_bfloat16* bbase = p2 + (size_t)(s0 + lo) * 64 + kg * 8;
    f32x4 acc[4][3];
#pragma unroll
    for (int ot = 0; ot < 4; ++ot)
#pragma unroll
        for (int u = 0; u < 3; ++u) acc[ot][u] = (f32x4){0.f, 0.f, 0.f, 0.f};

#pragma unroll
    for (int cb = 0; cb < 2; ++cb) {
        short8v B[12];
#pragma unroll
        for (int v = 0; v < 12; ++v)
            B[v] = *(const short8v*)(bbase + (size_t)(3 * tp + v) * 8192 + cb * 32);
#pragma unroll
        for (int ot = 0; ot < 4; ++ot) {
            if (oz && ot == 3) continue;
            const __hip_bfloat16* arow =
                W + (size_t)(oz * 64 + ot * 16 + lo) * 640 + cb * 32 + kg * 8;
#pragma unroll
            for (int kk = 0; kk < 10; ++kk) {
                short8v a = *(const short8v*)(arow + kk * 64);
#pragma unroll
                for (int u = 0; u < 3; ++u)
                    acc[ot][u] = __builtin_amdgcn_mfma_f32_16x16x32_bf16(a, B[kk + u], acc[ot][u], 0, 0, 0);
            }
        }
    }

    __hip_bfloat16* obase = p3 + (size_t)(tp * 128 + s0 + lo) * 128;
#pragma unroll
    for (int ot = 0; ot < 4; ++ot) {
        unsigned short uv[4];
#pragma unroll
        for (int e = 0; e < 4; ++e) {
            int o2 = oz * 64 + ot * 16 + kg * 4 + e;
            float val = 0.f;
            if (o2 < 100) {
                float m = fmaxf(fmaxf(acc[ot][0][e], acc[ot][1][e]), acc[ot][2][e]);
                val = eluf(m * ws[F_S3 + o2] + ws[F_H3 + o2]);
            }
            uv[e] = bfb(val);
        }
        uint2 pk = {(unsigned)uv[0] | ((unsigned)uv[1] << 16),
                    (unsigned)uv[2] | ((unsigned)uv[3] << 16)};
        *(uint2*)(obase + oz * 64 + ot * 16 + kg * 4) = pk;
    }
}

// ---------------- K4: L4 GEMM (100->200) + last-block fc/MoE heads ----------------
__global__ __launch_bounds__(256) void k_gemm4h(
    float* __restrict__ ws, const int* __restrict__ cids,
    const float* __restrict__ fcw, const float* __restrict__ fcb,
    const float* __restrict__ hW1, const float* __restrict__ hb1,
    const float* __restrict__ hW2, const float* __restrict__ hb2,
    float* __restrict__ out) {
    __hip_bfloat16* wsh = (__hip_bfloat16*)ws;
    const __hip_bfloat16* p3 = wsh + H_P3;
    const __hip_bfloat16* W = wsh + H_WA4;
    float* p4 = ws + F_P4;
    int tid = threadIdx.x;
    int w = blockIdx.x * 4 + (tid >> 6);                  // < 416
    int lane = tid & 63, lo = lane & 15, kg = lane >> 4;
    {
        int ot = w >> 5, ct = w & 31;
        int tp = ct >> 3, s0 = (ct & 7) * 16;
        const __hip_bfloat16* bbase = p3 + (size_t)(s0 + lo) * 128 + kg * 8;
        const __hip_bfloat16* arow0 = W + (size_t)(ot * 16 + lo) * 1280 + kg * 8;
        f32x4 acc[3];
#pragma unroll
        for (int u = 0; u < 3; ++u) acc[u] = (f32x4){0.f, 0.f, 0.f, 0.f};
#pragma unroll
        for (int cb = 0; cb < 4; ++cb) {
            short8v B[12];
#pragma unroll
            for (int v = 0; v < 12; ++v)
                B[v] = *(const short8v*)(bbase + (size_t)(3 * tp + v) * 16384 + cb * 32);
            const __hip_bfloat16* arow = arow0 + cb * 32;
#pragma unroll
            for (int kk = 0; kk < 10; ++kk) {
                short8v a = *(const short8v*)(arow + kk * 128);
#pragma unroll
                for (int u = 0; u < 3; ++u)
                    acc[u] = __builtin_amdgcn_mfma_f32_16x16x32_bf16(a, B[kk + u], acc[u], 0, 0, 0);
            }
        }
#pragma unroll
        for (int e = 0; e < 4; ++e) {
            int o2 = ot * 16 + kg * 4 + e;
            if (o2 < 200) {
                float m = fmaxf(fmaxf(acc[0][e], acc[1][e]), acc[2][e]);
                p4[((size_t)(s0 + lo) * 200 + o2) * 4 + tp] =
                    eluf(m * ws[F_S4 + o2] + ws[F_H4 + o2]);
            }
        }
    }

    // completion: last block of 104 runs the heads for all samples
    __shared__ unsigned lastFlag;
    __syncthreads();                  // drains this block's p4 stores (vmcnt0)
    if (tid == 0) {
        unsigned* cnt = (unsigned*)(ws + F_BAR);
        unsigned v = __hip_atomic_fetch_add(cnt, 1u, __ATOMIC_ACQ_REL,
                                            __HIP_MEMORY_SCOPE_AGENT);
        lastFlag = (v == 103u);
    }
    __syncthreads();
    if (!lastFlag) return;

    // heads: 2 threads per sample (c/hid split), shfl-combined
    int s = tid >> 1, half = tid & 1;
    const float* pp = p4 + (size_t)s * 800 + half * 400;
    float fcv[4] = {0.f, 0.f, 0.f, 0.f};
    for (int c = 0; c < 100; ++c) {
        const float* q = pp + c * 4;
        float v0 = q[0], v1 = q[1], v2 = q[2], v3 = q[3];
        int cg = half * 100 + c;
#pragma unroll
        for (int oo = 0; oo < 4; ++oo) {
            const float* fw = fcw + (oo * 200 + cg) * 4;
            fcv[oo] += fw[0] * v0 + fw[1] * v1 + fw[2] * v2 + fw[3] * v3;
        }
    }
    float fc[4];
#pragma unroll
    for (int oo = 0; oo < 4; ++oo)
        fc[oo] = fcv[oo] + __shfl_xor(fcv[oo], 1) + fcb[oo];

    int cid = cids[s];
    float o4[4] = {0.f, 0.f, 0.f, 0.f};
    for (int h = half * 64; h < half * 64 + 64; ++h) {
        float hv = hb1[cid * 128 + h];
#pragma unroll
        for (int f = 0; f < 4; ++f) hv += fc[f] * hW1[(cid * 4 + f) * 128 + h];
        hv = fmaxf(hv, 0.f);
#pragma unroll
        for (int oo = 0; oo < 4; ++oo) o4[oo] += hv * hW2[(cid * 128 + h) * 4 + oo];
    }
#pragma unroll
    for (int oo = 0; oo < 4; ++oo) o4[oo] += __shfl_xor(o4[oo], 1);
    if (!half) {
#pragma unroll
        for (int oo = 0; oo < 4; ++oo) out[s * 4 + oo] = o4[oo] + hb2[cid * 4 + oo];
    }
}

// ---------------- launch ----------------
extern "C" void kernel_launch(void* const* d_in, const int* in_sizes, int n_in,
                              void* d_out, int out_size, void* d_ws, size_t ws_size,
                              hipStream_t stream) {
    (void)in_sizes; (void)n_in; (void)out_size; (void)ws_size;
    const float* x    = (const float*)d_in[0];
    const int*   cid  = (const int*)d_in[1];
    const float* ctw  = (const float*)d_in[2];
    const float* ctb  = (const float*)d_in[3];
    const float* csw  = (const float*)d_in[4];
    const float* g1 = (const float*)d_in[5],  *b1 = (const float*)d_in[6];
    const float* m1 = (const float*)d_in[7],  *v1 = (const float*)d_in[8];
    const float* w2 = (const float*)d_in[9];
    const float* g2 = (const float*)d_in[10], *b2 = (const float*)d_in[11];
    const float* m2 = (const float*)d_in[12], *v2 = (const float*)d_in[13];
    const float* w3 = (const float*)d_in[14];
    const float* g3 = (const float*)d_in[15], *b3 = (const float*)d_in[16];
    const float* m3 = (const float*)d_in[17], *v3 = (const float*)d_in[18];
    const float* w4 = (const float*)d_in[19];
    const float* g4 = (const float*)d_in[20], *b4 = (const float*)d_in[21];
    const float* m4 = (const float*)d_in[22], *v4 = (const float*)d_in[23];
    const float* fcw = (const float*)d_in[24], *fcb = (const float*)d_in[25];
    const float* hW1 = (const float*)d_in[26], *hb1 = (const float*)d_in[27];
    const float* hW2 = (const float*)d_in[28], *hb2 = (const float*)d_in[29];
    float* ws  = (float*)d_ws;
    float* out = (float*)d_out;

    k_front<<<dim3(CONV_BLOCKS + CVT_BLOCKS), dim3(256), 0, stream>>>(
        x, ctw, ctb, csw, g1, b1, m1, v1, w2, g2, b2, m2, v2,
        w3, g3, b3, m3, v3, w4, g4, b4, m4, v4, ws);
    k_gemm2<<<dim3(316), dim3(256), 0, stream>>>(ws);
    k_gemm3<<<dim3(92),  dim3(256), 0, stream>>>(ws);
    k_gemm4h<<<dim3(104), dim3(256), 0, stream>>>(ws, cid, fcw, fcb,
                                                  hW1, hb1, hW2, hb2, out);
}

// Round 11
// 102.988 us; speedup vs baseline: 6.2845x; 1.4726x over previous
//
#include <hip/hip_runtime.h>
#include <hip/hip_bf16.h>
#include <math.h>

typedef __attribute__((ext_vector_type(8))) short short8v;
typedef __attribute__((ext_vector_type(4))) float f32x4;

// ---------------- ws layout ----------------
// float region:
#define F_S1 0
#define F_H1 32
#define F_S2 64
#define F_H2 128
#define F_S3 192
#define F_H3 320
#define F_S4 448
#define F_H4 704
#define F_B1 960
#define F_P4 1024        // 128*200*4 floats
#define F_END (1024 + 128*200*4)
// bf16 region:
#define H_BASE (F_END*2)
#define H_P1  H_BASE                    // [t=256][s=128][c=32] (t<247 written)
#define H_WA1 (H_P1 + 128*8192)         // 32*640   (o, kk*64+c)
#define H_WA2 (H_WA1 + 32*640)          // 64*320   (o, kk*32+c)
#define H_WA3 (H_WA2 + 64*320)          // 112*640  (o, kk*64+c)
#define H_WA4 (H_WA3 + 112*640)         // 208*1280 (o, kk*128+c)
#define H_P2  (H_WA4 + 208*1280)        // [t=79][s=128][c=64]
#define H_P3  (H_P2 + 79*128*64)        // [t=23][s=128][c=128]

#define N_WA1 (32*640)
#define N_WA2 (64*320)
#define N_WA3 (112*640)
#define N_WA4 (208*1280)
#define N_WTOT (N_WA1 + N_WA2 + N_WA3 + N_WA4)

__device__ __forceinline__ float eluf(float v) {
    return v > 0.f ? v : (expf(v) - 1.f);
}
__device__ __forceinline__ float ldh(const __hip_bfloat16* p) { return __bfloat162float(*p); }
__device__ __forceinline__ unsigned short bfb(float v) {
    __hip_bfloat16 h = __float2bfloat16(v);
    return reinterpret_cast<unsigned short&>(h);
}
__device__ __forceinline__ void ld4f(const float* p, float* v) {
    float2 a = *(const float2*)p, c = *(const float2*)(p + 2);
    v[0] = a.x; v[1] = a.y; v[2] = c.x; v[3] = c.y;
}

// ---------------- K0: precompute bf16 k-major weights + BN affines ----------------
__global__ __launch_bounds__(256) void k_pre2(
    const float* __restrict__ ct_w, const float* __restrict__ ct_b,
    const float* __restrict__ cs_w,
    const float* __restrict__ g1, const float* __restrict__ b1,
    const float* __restrict__ m1, const float* __restrict__ v1,
    const float* __restrict__ w2,
    const float* __restrict__ g2, const float* __restrict__ b2,
    const float* __restrict__ m2, const float* __restrict__ v2,
    const float* __restrict__ w3,
    const float* __restrict__ g3, const float* __restrict__ b3,
    const float* __restrict__ m3, const float* __restrict__ v3,
    const float* __restrict__ w4,
    const float* __restrict__ g4, const float* __restrict__ b4,
    const float* __restrict__ m4, const float* __restrict__ v4,
    float* __restrict__ ws) {
    __hip_bfloat16* wsh = (__hip_bfloat16*)ws;
    int t = blockIdx.x * 256 + threadIdx.x;
    if (t < N_WA1) {
        int o = t / 640, kv = t - o * 640, kk = kv / 64, c = kv - kk * 64;
        float s = 0.f;
        if (o < 25)
            for (int i = 0; i < 25; ++i)
                s += cs_w[(o * 25 + i) * 64 + c] * ct_w[i * 10 + kk];
        wsh[H_WA1 + t] = __float2bfloat16(s);
    } else if (t < N_WA1 + N_WA2) {
        int u = t - N_WA1;
        int o = u / 320, kv = u - o * 320, kk = kv / 32, c = kv - kk * 32;
        float s = (o < 50 && c < 25) ? w2[(o * 25 + c) * 10 + kk] : 0.f;
        wsh[H_WA2 + u] = __float2bfloat16(s);
    } else if (t < N_WA1 + N_WA2 + N_WA3) {
        int u = t - N_WA1 - N_WA2;
        int o = u / 640, kv = u - o * 640, kk = kv / 64, c = kv - kk * 64;
        float s = (o < 100 && c < 50) ? w3[(o * 50 + c) * 10 + kk] : 0.f;
        wsh[H_WA3 + u] = __float2bfloat16(s);
    } else if (t < N_WTOT) {
        int u = t - N_WA1 - N_WA2 - N_WA3;
        int o = u / 1280, kv = u - o * 1280, kk = kv / 128, c = kv - kk * 128;
        float s = (o < 200 && c < 100) ? w4[(o * 100 + c) * 10 + kk] : 0.f;
        wsh[H_WA4 + u] = __float2bfloat16(s);
    } else {
        int j = t - N_WTOT;
        if (j < 25) {
            float sc = g1[j] / sqrtf(v1[j] + 1e-5f);
            ws[F_S1 + j] = sc; ws[F_H1 + j] = b1[j] - m1[j] * sc;
        } else if (j >= 32 && j < 82) {
            int ch = j - 32;
            float sc = g2[ch] / sqrtf(v2[ch] + 1e-5f);
            ws[F_S2 + ch] = sc; ws[F_H2 + ch] = b2[ch] - m2[ch] * sc;
        } else if (j >= 96 && j < 196) {
            int ch = j - 96;
            float sc = g3[ch] / sqrtf(v3[ch] + 1e-5f);
            ws[F_S3 + ch] = sc; ws[F_H3 + ch] = b3[ch] - m3[ch] * sc;
        } else if (j >= 224 && j < 424) {
            int ch = j - 224;
            float sc = g4[ch] / sqrtf(v4[ch] + 1e-5f);
            ws[F_S4 + ch] = sc; ws[F_H4 + ch] = b4[ch] - m4[ch] * sc;
        } else if (j >= 448 && j < 473) {
            int o = j - 448;
            float s = 0.f;
            for (int i = 0; i < 25; ++i) {
                float cs = 0.f;
                for (int c = 0; c < 64; ++c) cs += cs_w[(o * 25 + i) * 64 + c];
                s += cs * ct_b[i];
            }
            ws[F_B1 + o] = s;
        }
    }
}

// ---------------- K1: conv1 + BN1 + ELU + pool3 ----------------
// grid (12, 128), 256 thr. 21 pooled/tile, LDS 14.3 KB -> high occupancy.
// Output p1 as [t][s][32] bf16 (c>=25 zero).
__global__ __launch_bounds__(256) void k_conv1(
    const float* __restrict__ x, float* __restrict__ ws) {
    __hip_bfloat16* wsh = (__hip_bfloat16*)ws;
    const __hip_bfloat16* Wa = wsh + H_WA1;
    int bx = blockIdx.x, b = blockIdx.y;
    int tp0 = bx * 21;
    int PTb = min(21, 247 - tp0);      // 21, last tile 16
    int t0 = 63 * bx;

    __shared__ __align__(16) __hip_bfloat16 xb[80 * 64];    // 10240 B, swizzled
    __shared__ __align__(16) __hip_bfloat16 eb[32 * 64];    // 4096 B

    // stage x: 80 rows x 64 ch, transposed, bf16, swizzled (rows >= valid -> 0)
    for (int f = threadIdx.x; f < 64 * 20; f += 256) {
        int c = f / 20, j = f - c * 20;
        int t = t0 + 4 * j;
        const float* src = x + ((size_t)b * 64 + c) * 750 + t;
        float v[4];
        if (t + 3 < 750) {
            ld4f(src, v);
        } else {
#pragma unroll
            for (int e = 0; e < 4; ++e) v[e] = (t + e < 750) ? src[e] : 0.f;
        }
#pragma unroll
        for (int e = 0; e < 4; ++e) {
            int r = 4 * j + e;
            xb[r * 64 + (c ^ (8 * (r & 7)))] = __float2bfloat16(v[e]);
        }
    }
    __syncthreads();

    // MFMA: 4 waves -> (ot 0..1, ctg 0..1); each wave 2 col-tiles, NS=20
    int lane = threadIdx.x & 63, wid = threadIdx.x >> 6;
    int lo = lane & 15, kg = lane >> 4;
    int ot = wid >> 1, ctg = wid & 1;
    const short8v* Ap = (const short8v*)(Wa + (size_t)(ot * 16 + lo) * 640);
    f32x4 acc[2];
#pragma unroll
    for (int q = 0; q < 2; ++q) acc[q] = (f32x4){0.f, 0.f, 0.f, 0.f};
#pragma unroll 1
    for (int sb = 0; sb < 20; sb += 10) {
        short8v af[10];
#pragma unroll
        for (int u = 0; u < 10; ++u) af[u] = Ap[(sb + u) * 4 + kg];
#pragma unroll
        for (int u = 0; u < 10; ++u) {
            int s = sb + u;
            int kk = s >> 1, cb = s & 1;
#pragma unroll
            for (int q = 0; q < 2; ++q) {
                int r = (ctg * 2 + q) * 16 + lo + kk;     // <= 72 < 80
                int cs = (cb * 32 + kg * 8) ^ (8 * (r & 7));
                short8v bf = *(const short8v*)&xb[r * 64 + cs];
                acc[q] = __builtin_amdgcn_mfma_f32_16x16x32_bf16(af[u], bf, acc[q], 0, 0, 0);
            }
        }
    }
#pragma unroll
    for (int q = 0; q < 2; ++q) {
        int tloc = (ctg * 2 + q) * 16 + lo;               // < 64
#pragma unroll
        for (int e = 0; e < 4; ++e) {
            int o2 = ot * 16 + kg * 4 + e;                // < 32
            float a = acc[q][e] + ws[F_B1 + o2];
            eb[o2 * 64 + tloc] = __float2bfloat16(eluf(a * ws[F_S1 + o2] + ws[F_H1 + o2]));
        }
    }
    __syncthreads();

    // pool + store [t][s][32] (og fastest -> coalesced 64B lines)
    __hip_bfloat16* p1g = wsh + H_P1;
    for (int i = threadIdx.x; i < 21 * 8; i += 256) {
        int pl = i >> 3, og = i & 7;
        if (pl < PTb) {
            int tp = tp0 + pl;
            unsigned short uv[4];
#pragma unroll
            for (int j = 0; j < 4; ++j) {
                int o = og * 4 + j;
                float v = 0.f;
                if (o < 25) {
                    const __hip_bfloat16* ep = eb + o * 64 + 3 * pl;
                    v = fmaxf(fmaxf(ldh(ep), ldh(ep + 1)), ldh(ep + 2));
                }
                uv[j] = bfb(v);
            }
            uint2 pk = {(unsigned)uv[0] | ((unsigned)uv[1] << 16),
                        (unsigned)uv[2] | ((unsigned)uv[3] << 16)};
            *(uint2*)(p1g + (size_t)tp * 4096 + b * 32 + og * 4) = pk;
        }
    }
}

// ---------------- K2: L2 batched GEMM (25->50), B reused over 2 ot ----------------
__global__ __launch_bounds__(256) void k_gemm2(float* __restrict__ ws) {
    __hip_bfloat16* wsh = (__hip_bfloat16*)ws;
    const __hip_bfloat16* p1 = wsh + H_P1;
    const __hip_bfloat16* W = wsh + H_WA2;
    __hip_bfloat16* p2 = wsh + H_P2;
    int w = blockIdx.x * 4 + (threadIdx.x >> 6);          // < 1264
    int lane = threadIdx.x & 63, lo = lane & 15, kg = lane >> 4;
    int otp = w & 1, cw = w >> 1;
    int tp = cw >> 3, s0 = (cw & 7) * 16;

    const __hip_bfloat16* bbase = p1 + (size_t)(s0 + lo) * 32 + kg * 8;
    short8v B[12];
#pragma unroll
    for (int v = 0; v < 12; ++v)
        B[v] = *(const short8v*)(bbase + (size_t)(3 * tp + v) * 4096);
#pragma unroll
    for (int oi = 0; oi < 2; ++oi) {
        int ot = otp * 2 + oi;
        f32x4 acc[3];
#pragma unroll
        for (int u = 0; u < 3; ++u) acc[u] = (f32x4){0.f, 0.f, 0.f, 0.f};
        const __hip_bfloat16* arow = W + (size_t)(ot * 16 + lo) * 320 + kg * 8;
#pragma unroll
        for (int kk = 0; kk < 10; ++kk) {
            short8v a = *(const short8v*)(arow + kk * 32);
#pragma unroll
            for (int u = 0; u < 3; ++u)
                acc[u] = __builtin_amdgcn_mfma_f32_16x16x32_bf16(a, B[kk + u], acc[u], 0, 0, 0);
        }
        unsigned short uv[4];
#pragma unroll
        for (int e = 0; e < 4; ++e) {
            int o2 = ot * 16 + kg * 4 + e;
            float m = fmaxf(fmaxf(acc[0][e], acc[1][e]), acc[2][e]);
            uv[e] = bfb((o2 < 50) ? eluf(m * ws[F_S2 + o2] + ws[F_H2 + o2]) : 0.f);
        }
        uint2 pk = {(unsigned)uv[0] | ((unsigned)uv[1] << 16),
                    (unsigned)uv[2] | ((unsigned)uv[3] << 16)};
        *(uint2*)(p2 + (size_t)(tp * 128 + s0 + lo) * 64 + ot * 16 + kg * 4) = pk;
    }
}

// ---------------- K3: L3 batched GEMM (50->100) ----------------
__global__ __launch_bounds__(256) void k_gemm3(float* __restrict__ ws) {
    __hip_bfloat16* wsh = (__hip_bfloat16*)ws;
    const __hip_bfloat16* p2 = wsh + H_P2;
    const __hip_bfloat16* W = wsh + H_WA3;
    __hip_bfloat16* p3 = wsh + H_P3;
    int w = blockIdx.x * 4 + (threadIdx.x >> 6);          // < 368
    int lane = threadIdx.x & 63, lo = lane & 15, kg = lane >> 4;
    int col = w >> 1, oz = w & 1;
    int tp = col >> 3, s0 = (col & 7) * 16;

    const __hip_bfloat16* bbase = p2 + (size_t)(s0 + lo) * 64 + kg * 8;
    f32x4 acc[4][3];
#pragma unroll
    for (int ot = 0; ot < 4; ++ot)
#pragma unroll
        for (int u = 0; u < 3; ++u) acc[ot][u] = (f32x4){0.f, 0.f, 0.f, 0.f};

#pragma unroll
    for (int cb = 0; cb < 2; ++cb) {
        short8v B[12];
#pragma unroll
        for (int v = 0; v < 12; ++v)
            B[v] = *(const short8v*)(bbase + (size_t)(3 * tp + v) * 8192 + cb * 32);
#pragma unroll
        for (int ot = 0; ot < 4; ++ot) {
            if (oz && ot == 3) continue;
            const __hip_bfloat16* arow =
                W + (size_t)(oz * 64 + ot * 16 + lo) * 640 + cb * 32 + kg * 8;
#pragma unroll
            for (int kk = 0; kk < 10; ++kk) {
                short8v a = *(const short8v*)(arow + kk * 64);
#pragma unroll
                for (int u = 0; u < 3; ++u)
                    acc[ot][u] = __builtin_amdgcn_mfma_f32_16x16x32_bf16(a, B[kk + u], acc[ot][u], 0, 0, 0);
            }
        }
    }

    __hip_bfloat16* obase = p3 + (size_t)(tp * 128 + s0 + lo) * 128;
#pragma unroll
    for (int ot = 0; ot < 4; ++ot) {
        unsigned short uv[4];
#pragma unroll
        for (int e = 0; e < 4; ++e) {
            int o2 = oz * 64 + ot * 16 + kg * 4 + e;
            float val = 0.f;
            if (o2 < 100) {
                float m = fmaxf(fmaxf(acc[ot][0][e], acc[ot][1][e]), acc[ot][2][e]);
                val = eluf(m * ws[F_S3 + o2] + ws[F_H3 + o2]);
            }
            uv[e] = bfb(val);
        }
        uint2 pk = {(unsigned)uv[0] | ((unsigned)uv[1] << 16),
                    (unsigned)uv[2] | ((unsigned)uv[3] << 16)};
        *(uint2*)(obase + oz * 64 + ot * 16 + kg * 4) = pk;
    }
}

// ---------------- K4: L4 batched GEMM (100->200), fp32 out [s][o][4] ----------------
__global__ __launch_bounds__(256) void k_gemm4(float* __restrict__ ws) {
    __hip_bfloat16* wsh = (__hip_bfloat16*)ws;
    const __hip_bfloat16* p3 = wsh + H_P3;
    const __hip_bfloat16* W = wsh + H_WA4;
    float* p4 = ws + F_P4;
    int w = blockIdx.x * 4 + (threadIdx.x >> 6);          // < 416
    int lane = threadIdx.x & 63, lo = lane & 15, kg = lane >> 4;
    int ot = w >> 5, ct = w & 31;
    int tp = ct >> 3, s0 = (ct & 7) * 16;

    const __hip_bfloat16* bbase = p3 + (size_t)(s0 + lo) * 128 + kg * 8;
    const __hip_bfloat16* arow0 = W + (size_t)(ot * 16 + lo) * 1280 + kg * 8;
    f32x4 acc[3];
#pragma unroll
    for (int u = 0; u < 3; ++u) acc[u] = (f32x4){0.f, 0.f, 0.f, 0.f};

#pragma unroll
    for (int cb = 0; cb < 4; ++cb) {
        short8v B[12];
#pragma unroll
        for (int v = 0; v < 12; ++v)
            B[v] = *(const short8v*)(bbase + (size_t)(3 * tp + v) * 16384 + cb * 32);
        const __hip_bfloat16* arow = arow0 + cb * 32;
#pragma unroll
        for (int kk = 0; kk < 10; ++kk) {
            short8v a = *(const short8v*)(arow + kk * 128);
#pragma unroll
            for (int u = 0; u < 3; ++u)
                acc[u] = __builtin_amdgcn_mfma_f32_16x16x32_bf16(a, B[kk + u], acc[u], 0, 0, 0);
        }
    }

#pragma unroll
    for (int e = 0; e < 4; ++e) {
        int o2 = ot * 16 + kg * 4 + e;
        if (o2 < 200) {
            float m = fmaxf(fmaxf(acc[0][e], acc[1][e]), acc[2][e]);
            p4[((size_t)(s0 + lo) * 200 + o2) * 4 + tp] =
                eluf(m * ws[F_S4 + o2] + ws[F_H4 + o2]);
        }
    }
}

// ---------------- K5: fc conv + per-sample MoE heads ----------------
__global__ __launch_bounds__(128) void k_heads(
    const float* __restrict__ ws,
    const float* __restrict__ fcw, const float* __restrict__ fcb,
    const int* __restrict__ cids,
    const float* __restrict__ hW1, const float* __restrict__ hb1,
    const float* __restrict__ hW2, const float* __restrict__ hb2,
    float* __restrict__ out) {
    const float* p4 = ws + F_P4;
    __shared__ float red[4][128];
    __shared__ float fs[4];
    int b = blockIdx.x, j = threadIdx.x;

    float pa[4] = {0.f, 0.f, 0.f, 0.f};
    for (int c = j; c < 200; c += 128) {
        const float* pp = p4 + ((size_t)b * 200 + c) * 4;
        float v0 = pp[0], v1 = pp[1], v2 = pp[2], v3 = pp[3];
#pragma unroll
        for (int o = 0; o < 4; ++o) {
            const float* fw = fcw + (o * 200 + c) * 4;
            pa[o] += fw[0] * v0 + fw[1] * v1 + fw[2] * v2 + fw[3] * v3;
        }
    }
#pragma unroll
    for (int o = 0; o < 4; ++o) red[o][j] = pa[o];
    __syncthreads();
    for (int s = 64; s > 0; s >>= 1) {
        if (j < s) {
#pragma unroll
            for (int o = 0; o < 4; ++o) red[o][j] += red[o][j + s];
        }
        __syncthreads();
    }
    if (j < 4) fs[j] = red[j][0] + fcb[j];
    __syncthreads();

    int cid = cids[b];
    float hvv = hb1[cid * 128 + j];
#pragma unroll
    for (int f = 0; f < 4; ++f) hvv += fs[f] * hW1[(cid * 4 + f) * 128 + j];
    hvv = fmaxf(hvv, 0.f);
#pragma unroll
    for (int o = 0; o < 4; ++o) red[o][j] = hvv * hW2[(cid * 128 + j) * 4 + o];
    __syncthreads();
    for (int s = 64; s > 0; s >>= 1) {
        if (j < s) {
#pragma unroll
            for (int o = 0; o < 4; ++o) red[o][j] += red[o][j + s];
        }
        __syncthreads();
    }
    if (j < 4) out[b * 4 + j] = red[j][0] + hb2[cid * 4 + j];
}

// ---------------- launch ----------------
extern "C" void kernel_launch(void* const* d_in, const int* in_sizes, int n_in,
                              void* d_out, int out_size, void* d_ws, size_t ws_size,
                              hipStream_t stream) {
    (void)in_sizes; (void)n_in; (void)out_size; (void)ws_size;
    const float* x    = (const float*)d_in[0];
    const int*   cid  = (const int*)d_in[1];
    const float* ctw  = (const float*)d_in[2];
    const float* ctb  = (const float*)d_in[3];
    const float* csw  = (const float*)d_in[4];
    const float* g1 = (const float*)d_in[5],  *b1 = (const float*)d_in[6];
    const float* m1 = (const float*)d_in[7],  *v1 = (const float*)d_in[8];
    const float* w2 = (const float*)d_in[9];
    const float* g2 = (const float*)d_in[10], *b2 = (const float*)d_in[11];
    const float* m2 = (const float*)d_in[12], *v2 = (const float*)d_in[13];
    const float* w3 = (const float*)d_in[14];
    const float* g3 = (const float*)d_in[15], *b3 = (const float*)d_in[16];
    const float* m3 = (const float*)d_in[17], *v3 = (const float*)d_in[18];
    const float* w4 = (const float*)d_in[19];
    const float* g4 = (const float*)d_in[20], *b4 = (const float*)d_in[21];
    const float* m4 = (const float*)d_in[22], *v4 = (const float*)d_in[23];
    const float* fcw = (const float*)d_in[24], *fcb = (const float*)d_in[25];
    const float* hW1 = (const float*)d_in[26], *hb1 = (const float*)d_in[27];
    const float* hW2 = (const float*)d_in[28], *hb2 = (const float*)d_in[29];
    float* ws  = (float*)d_ws;
    float* out = (float*)d_out;

    k_pre2<<<dim3((N_WTOT + 512 + 255) / 256), dim3(256), 0, stream>>>(
        ctw, ctb, csw, g1, b1, m1, v1, w2, g2, b2, m2, v2,
        w3, g3, b3, m3, v3, w4, g4, b4, m4, v4, ws);
    k_conv1<<<dim3(12, 128), dim3(256), 0, stream>>>(x, ws);
    k_gemm2<<<dim3(316), dim3(256), 0, stream>>>(ws);
    k_gemm3<<<dim3(92),  dim3(256), 0, stream>>>(ws);
    k_gemm4<<<dim3(104), dim3(256), 0, stream>>>(ws);
    k_heads<<<dim3(128), dim3(128), 0, stream>>>(ws, fcw, fcb, cid,
                                                 hW1, hb1, hW2, hb2, out);
}

// Round 12
// 95.684 us; speedup vs baseline: 6.7642x; 1.0763x over previous
//
#include <hip/hip_runtime.h>
#include <hip/hip_bf16.h>
#include <math.h>

typedef __attribute__((ext_vector_type(8))) short short8v;
typedef __attribute__((ext_vector_type(4))) float f32x4;

// ---------------- ws layout ----------------
// float region:
#define F_S1 0
#define F_H1 32
#define F_S2 64
#define F_H2 128
#define F_S3 192
#define F_H3 320
#define F_S4 448
#define F_H4 704
#define F_B1 960
#define F_P4 1024        // 128*200*4 floats
#define F_END (1024 + 128*200*4)
// bf16 region:
#define H_BASE (F_END*2)
#define H_P1  H_BASE                    // [t=256][s=128][c=32] (t<247 written)
#define H_WA1 (H_P1 + 128*8192)         // 32*640   (o, kk*64+c)
#define H_WA2 (H_WA1 + 32*640)          // 64*320   (o, kk*32+c)
#define H_WA3 (H_WA2 + 64*320)          // 112*640  (o, kk*64+c)
#define H_WA4 (H_WA3 + 112*640)         // 208*1280 (o, kk*128+c)
#define H_P2  (H_WA4 + 208*1280)        // [t=79][s=128][c=64]
#define H_P3  (H_P2 + 79*128*64)        // [t=23][s=128][c=128]

#define N_WA1 (32*640)
#define N_WA2 (64*320)
#define N_WA3 (112*640)
#define N_WA4 (208*1280)
#define N_WTOT (N_WA1 + N_WA2 + N_WA3 + N_WA4)

__device__ __forceinline__ float eluf(float v) {
    return v > 0.f ? v : (expf(v) - 1.f);
}
__device__ __forceinline__ float ldh(const __hip_bfloat16* p) { return __bfloat162float(*p); }
__device__ __forceinline__ unsigned short bfb(float v) {
    __hip_bfloat16 h = __float2bfloat16(v);
    return reinterpret_cast<unsigned short&>(h);
}
__device__ __forceinline__ void ld4f(const float* p, float* v) {
    float2 a = *(const float2*)p, c = *(const float2*)(p + 2);
    v[0] = a.x; v[1] = a.y; v[2] = c.x; v[3] = c.y;
}

// ---------------- K0: precompute bf16 k-major weights + BN affines ----------------
__global__ __launch_bounds__(256) void k_pre2(
    const float* __restrict__ ct_w, const float* __restrict__ ct_b,
    const float* __restrict__ cs_w,
    const float* __restrict__ g1, const float* __restrict__ b1,
    const float* __restrict__ m1, const float* __restrict__ v1,
    const float* __restrict__ w2,
    const float* __restrict__ g2, const float* __restrict__ b2,
    const float* __restrict__ m2, const float* __restrict__ v2,
    const float* __restrict__ w3,
    const float* __restrict__ g3, const float* __restrict__ b3,
    const float* __restrict__ m3, const float* __restrict__ v3,
    const float* __restrict__ w4,
    const float* __restrict__ g4, const float* __restrict__ b4,
    const float* __restrict__ m4, const float* __restrict__ v4,
    float* __restrict__ ws) {
    __hip_bfloat16* wsh = (__hip_bfloat16*)ws;
    int t = blockIdx.x * 256 + threadIdx.x;
    if (t < N_WA1) {
        int o = t / 640, kv = t - o * 640, kk = kv / 64, c = kv - kk * 64;
        float s = 0.f;
        if (o < 25)
            for (int i = 0; i < 25; ++i)
                s += cs_w[(o * 25 + i) * 64 + c] * ct_w[i * 10 + kk];
        wsh[H_WA1 + t] = __float2bfloat16(s);
    } else if (t < N_WA1 + N_WA2) {
        int u = t - N_WA1;
        int o = u / 320, kv = u - o * 320, kk = kv / 32, c = kv - kk * 32;
        float s = (o < 50 && c < 25) ? w2[(o * 25 + c) * 10 + kk] : 0.f;
        wsh[H_WA2 + u] = __float2bfloat16(s);
    } else if (t < N_WA1 + N_WA2 + N_WA3) {
        int u = t - N_WA1 - N_WA2;
        int o = u / 640, kv = u - o * 640, kk = kv / 64, c = kv - kk * 64;
        float s = (o < 100 && c < 50) ? w3[(o * 50 + c) * 10 + kk] : 0.f;
        wsh[H_WA3 + u] = __float2bfloat16(s);
    } else if (t < N_WTOT) {
        int u = t - N_WA1 - N_WA2 - N_WA3;
        int o = u / 1280, kv = u - o * 1280, kk = kv / 128, c = kv - kk * 128;
        float s = (o < 200 && c < 100) ? w4[(o * 100 + c) * 10 + kk] : 0.f;
        wsh[H_WA4 + u] = __float2bfloat16(s);
    } else {
        int j = t - N_WTOT;
        if (j < 25) {
            float sc = g1[j] / sqrtf(v1[j] + 1e-5f);
            ws[F_S1 + j] = sc; ws[F_H1 + j] = b1[j] - m1[j] * sc;
        } else if (j >= 32 && j < 82) {
            int ch = j - 32;
            float sc = g2[ch] / sqrtf(v2[ch] + 1e-5f);
            ws[F_S2 + ch] = sc; ws[F_H2 + ch] = b2[ch] - m2[ch] * sc;
        } else if (j >= 96 && j < 196) {
            int ch = j - 96;
            float sc = g3[ch] / sqrtf(v3[ch] + 1e-5f);
            ws[F_S3 + ch] = sc; ws[F_H3 + ch] = b3[ch] - m3[ch] * sc;
        } else if (j >= 224 && j < 424) {
            int ch = j - 224;
            float sc = g4[ch] / sqrtf(v4[ch] + 1e-5f);
            ws[F_S4 + ch] = sc; ws[F_H4 + ch] = b4[ch] - m4[ch] * sc;
        } else if (j >= 448 && j < 473) {
            int o = j - 448;
            float s = 0.f;
            for (int i = 0; i < 25; ++i) {
                float cs = 0.f;
                for (int c = 0; c < 64; ++c) cs += cs_w[(o * 25 + i) * 64 + c];
                s += cs * ct_b[i];
            }
            ws[F_B1 + o] = s;
        }
    }
}

// ---------------- K1: conv1 + BN1 + ELU + pool3 ----------------
// grid (8, 128), 256 thr. PT=31 pooled/tile, rows 112 (104 staged + 8 zero),
// 6 coltiles; waves = (ot 0..1, ctg 0..1) x 3 ct each = 60 MFMA/wave.
// af chunk = 5 (20 VGPR) to keep register pressure low.
__global__ __launch_bounds__(256) void k_conv1(
    const float* __restrict__ x, float* __restrict__ ws) {
    __hip_bfloat16* wsh = (__hip_bfloat16*)ws;
    const __hip_bfloat16* Wa = wsh + H_WA1;
    int bx = blockIdx.x, b = blockIdx.y;
    int tp0 = bx * 31;
    int PTb = min(31, 247 - tp0);      // 31, last tile 30
    int t0 = 93 * bx;

    __shared__ __align__(16) __hip_bfloat16 xb[112 * 64];   // 14336 B, swizzled
    __shared__ __align__(16) __hip_bfloat16 eb[32 * 96];    // 6144 B

    // zero rows 104..111 (MFMA over-read region)
    for (int i = threadIdx.x; i < 8 * 64; i += 256) {
        int r = 104 + (i >> 6), c = i & 63;
        xb[r * 64 + c] = __float2bfloat16(0.f);
    }
    // stage x: 104 rows x 64 ch, transposed, bf16, swizzled
    for (int f = threadIdx.x; f < 64 * 26; f += 256) {
        int c = f / 26, j = f - c * 26;
        int t = t0 + 4 * j;
        const float* src = x + ((size_t)b * 64 + c) * 750 + t;
        float v[4];
        if (t + 3 < 750) {
            ld4f(src, v);
        } else {
#pragma unroll
            for (int e = 0; e < 4; ++e) v[e] = (t + e < 750) ? src[e] : 0.f;
        }
#pragma unroll
        for (int e = 0; e < 4; ++e) {
            int r = 4 * j + e;
            xb[r * 64 + (c ^ (8 * (r & 7)))] = __float2bfloat16(v[e]);
        }
    }
    __syncthreads();

    // MFMA: 4 waves -> (ot 0..1, ctg 0..1); each wave 3 col-tiles, NS=20
    int lane = threadIdx.x & 63, wid = threadIdx.x >> 6;
    int lo = lane & 15, kg = lane >> 4;
    int ot = wid >> 1, ctg = wid & 1;
    const short8v* Ap = (const short8v*)(Wa + (size_t)(ot * 16 + lo) * 640);
    f32x4 acc[3];
#pragma unroll
    for (int q = 0; q < 3; ++q) acc[q] = (f32x4){0.f, 0.f, 0.f, 0.f};
#pragma unroll 1
    for (int sb = 0; sb < 20; sb += 5) {
        short8v af[5];
#pragma unroll
        for (int u = 0; u < 5; ++u) af[u] = Ap[(sb + u) * 4 + kg];
#pragma unroll
        for (int u = 0; u < 5; ++u) {
            int s = sb + u;
            int kk = s >> 1, cb = s & 1;
#pragma unroll
            for (int q = 0; q < 3; ++q) {
                int r = (ctg * 3 + q) * 16 + lo + kk;     // <= 104 < 112
                int cs = (cb * 32 + kg * 8) ^ (8 * (r & 7));
                short8v bf = *(const short8v*)&xb[r * 64 + cs];
                acc[q] = __builtin_amdgcn_mfma_f32_16x16x32_bf16(af[u], bf, acc[q], 0, 0, 0);
            }
        }
    }
#pragma unroll
    for (int q = 0; q < 3; ++q) {
        int tloc = (ctg * 3 + q) * 16 + lo;               // < 96
#pragma unroll
        for (int e = 0; e < 4; ++e) {
            int o2 = ot * 16 + kg * 4 + e;                // < 32
            float a = acc[q][e] + ws[F_B1 + o2];
            eb[o2 * 96 + tloc] = __float2bfloat16(eluf(a * ws[F_S1 + o2] + ws[F_H1 + o2]));
        }
    }
    __syncthreads();

    // pool + store [t][s][32] (og fastest -> coalesced 64B lines)
    __hip_bfloat16* p1g = wsh + H_P1;
    for (int i = threadIdx.x; i < 31 * 8; i += 256) {
        int pl = i >> 3, og = i & 7;
        if (pl < PTb) {
            int tp = tp0 + pl;
            unsigned short uv[4];
#pragma unroll
            for (int j = 0; j < 4; ++j) {
                int o = og * 4 + j;
                float v = 0.f;
                if (o < 25) {
                    const __hip_bfloat16* ep = eb + o * 96 + 3 * pl;
                    v = fmaxf(fmaxf(ldh(ep), ldh(ep + 1)), ldh(ep + 2));
                }
                uv[j] = bfb(v);
            }
            uint2 pk = {(unsigned)uv[0] | ((unsigned)uv[1] << 16),
                        (unsigned)uv[2] | ((unsigned)uv[3] << 16)};
            *(uint2*)(p1g + (size_t)tp * 4096 + b * 32 + og * 4) = pk;
        }
    }
}

// ---------------- K2: L2 batched GEMM (25->50), B reused over 2 ot ----------------
__global__ __launch_bounds__(256) void k_gemm2(float* __restrict__ ws) {
    __hip_bfloat16* wsh = (__hip_bfloat16*)ws;
    const __hip_bfloat16* p1 = wsh + H_P1;
    const __hip_bfloat16* W = wsh + H_WA2;
    __hip_bfloat16* p2 = wsh + H_P2;
    int w = blockIdx.x * 4 + (threadIdx.x >> 6);          // < 1264
    int lane = threadIdx.x & 63, lo = lane & 15, kg = lane >> 4;
    int otp = w & 1, cw = w >> 1;
    int tp = cw >> 3, s0 = (cw & 7) * 16;

    const __hip_bfloat16* bbase = p1 + (size_t)(s0 + lo) * 32 + kg * 8;
    short8v B[12];
#pragma unroll
    for (int v = 0; v < 12; ++v)
        B[v] = *(const short8v*)(bbase + (size_t)(3 * tp + v) * 4096);
#pragma unroll
    for (int oi = 0; oi < 2; ++oi) {
        int ot = otp * 2 + oi;
        f32x4 acc[3];
#pragma unroll
        for (int u = 0; u < 3; ++u) acc[u] = (f32x4){0.f, 0.f, 0.f, 0.f};
        const __hip_bfloat16* arow = W + (size_t)(ot * 16 + lo) * 320 + kg * 8;
#pragma unroll
        for (int kk = 0; kk < 10; ++kk) {
            short8v a = *(const short8v*)(arow + kk * 32);
#pragma unroll
            for (int u = 0; u < 3; ++u)
                acc[u] = __builtin_amdgcn_mfma_f32_16x16x32_bf16(a, B[kk + u], acc[u], 0, 0, 0);
        }
        unsigned short uv[4];
#pragma unroll
        for (int e = 0; e < 4; ++e) {
            int o2 = ot * 16 + kg * 4 + e;
            float m = fmaxf(fmaxf(acc[0][e], acc[1][e]), acc[2][e]);
            uv[e] = bfb((o2 < 50) ? eluf(m * ws[F_S2 + o2] + ws[F_H2 + o2]) : 0.f);
        }
        uint2 pk = {(unsigned)uv[0] | ((unsigned)uv[1] << 16),
                    (unsigned)uv[2] | ((unsigned)uv[3] << 16)};
        *(uint2*)(p2 + (size_t)(tp * 128 + s0 + lo) * 64 + ot * 16 + kg * 4) = pk;
    }
}

// ---------------- K3: L3 batched GEMM (50->100) ----------------
__global__ __launch_bounds__(256) void k_gemm3(float* __restrict__ ws) {
    __hip_bfloat16* wsh = (__hip_bfloat16*)ws;
    const __hip_bfloat16* p2 = wsh + H_P2;
    const __hip_bfloat16* W = wsh + H_WA3;
    __hip_bfloat16* p3 = wsh + H_P3;
    int w = blockIdx.x * 4 + (threadIdx.x >> 6);          // < 368
    int lane = threadIdx.x & 63, lo = lane & 15, kg = lane >> 4;
    int col = w >> 1, oz = w & 1;
    int tp = col >> 3, s0 = (col & 7) * 16;

    const __hip_bfloat16* bbase = p2 + (size_t)(s0 + lo) * 64 + kg * 8;
    f32x4 acc[4][3];
#pragma unroll
    for (int ot = 0; ot < 4; ++ot)
#pragma unroll
        for (int u = 0; u < 3; ++u) acc[ot][u] = (f32x4){0.f, 0.f, 0.f, 0.f};

#pragma unroll
    for (int cb = 0; cb < 2; ++cb) {
        short8v B[12];
#pragma unroll
        for (int v = 0; v < 12; ++v)
            B[v] = *(const short8v*)(bbase + (size_t)(3 * tp + v) * 8192 + cb * 32);
#pragma unroll
        for (int ot = 0; ot < 4; ++ot) {
            if (oz && ot == 3) continue;
            const __hip_bfloat16* arow =
                W + (size_t)(oz * 64 + ot * 16 + lo) * 640 + cb * 32 + kg * 8;
#pragma unroll
            for (int kk = 0; kk < 10; ++kk) {
                short8v a = *(const short8v*)(arow + kk * 64);
#pragma unroll
                for (int u = 0; u < 3; ++u)
                    acc[ot][u] = __builtin_amdgcn_mfma_f32_16x16x32_bf16(a, B[kk + u], acc[ot][u], 0, 0, 0);
            }
        }
    }

    __hip_bfloat16* obase = p3 + (size_t)(tp * 128 + s0 + lo) * 128;
#pragma unroll
    for (int ot = 0; ot < 4; ++ot) {
        unsigned short uv[4];
#pragma unroll
        for (int e = 0; e < 4; ++e) {
            int o2 = oz * 64 + ot * 16 + kg * 4 + e;
            float val = 0.f;
            if (o2 < 100) {
                float m = fmaxf(fmaxf(acc[ot][0][e], acc[ot][1][e]), acc[ot][2][e]);
                val = eluf(m * ws[F_S3 + o2] + ws[F_H3 + o2]);
            }
            uv[e] = bfb(val);
        }
        uint2 pk = {(unsigned)uv[0] | ((unsigned)uv[1] << 16),
                    (unsigned)uv[2] | ((unsigned)uv[3] << 16)};
        *(uint2*)(obase + oz * 64 + ot * 16 + kg * 4) = pk;
    }
}

// ---------------- K4: L4 batched GEMM (100->200), fp32 out [s][o][4] ----------------
__global__ __launch_bounds__(256) void k_gemm4(float* __restrict__ ws) {
    __hip_bfloat16* wsh = (__hip_bfloat16*)ws;
    const __hip_bfloat16* p3 = wsh + H_P3;
    const __hip_bfloat16* W = wsh + H_WA4;
    float* p4 = ws + F_P4;
    int w = blockIdx.x * 4 + (threadIdx.x >> 6);          // < 416
    int lane = threadIdx.x & 63, lo = lane & 15, kg = lane >> 4;
    int ot = w >> 5, ct = w & 31;
    int tp = ct >> 3, s0 = (ct & 7) * 16;

    const __hip_bfloat16* bbase = p3 + (size_t)(s0 + lo) * 128 + kg * 8;
    const __hip_bfloat16* arow0 = W + (size_t)(ot * 16 + lo) * 1280 + kg * 8;
    f32x4 acc[3];
#pragma unroll
    for (int u = 0; u < 3; ++u) acc[u] = (f32x4){0.f, 0.f, 0.f, 0.f};

#pragma unroll
    for (int cb = 0; cb < 4; ++cb) {
        short8v B[12];
#pragma unroll
        for (int v = 0; v < 12; ++v)
            B[v] = *(const short8v*)(bbase + (size_t)(3 * tp + v) * 16384 + cb * 32);
        const __hip_bfloat16* arow = arow0 + cb * 32;
#pragma unroll
        for (int kk = 0; kk < 10; ++kk) {
            short8v a = *(const short8v*)(arow + kk * 128);
#pragma unroll
            for (int u = 0; u < 3; ++u)
                acc[u] = __builtin_amdgcn_mfma_f32_16x16x32_bf16(a, B[kk + u], acc[u], 0, 0, 0);
        }
    }

#pragma unroll
    for (int e = 0; e < 4; ++e) {
        int o2 = ot * 16 + kg * 4 + e;
        if (o2 < 200) {
            float m = fmaxf(fmaxf(acc[0][e], acc[1][e]), acc[2][e]);
            p4[((size_t)(s0 + lo) * 200 + o2) * 4 + tp] =
                eluf(m * ws[F_S4 + o2] + ws[F_H4 + o2]);
        }
    }
}

// ---------------- K5: fc conv + per-sample MoE heads ----------------
__global__ __launch_bounds__(128) void k_heads(
    const float* __restrict__ ws,
    const float* __restrict__ fcw, const float* __restrict__ fcb,
    const int* __restrict__ cids,
    const float* __restrict__ hW1, const float* __restrict__ hb1,
    const float* __restrict__ hW2, const float* __restrict__ hb2,
    float* __restrict__ out) {
    const float* p4 = ws + F_P4;
    __shared__ float red[4][128];
    __shared__ float fs[4];
    int b = blockIdx.x, j = threadIdx.x;

    float pa[4] = {0.f, 0.f, 0.f, 0.f};
    for (int c = j; c < 200; c += 128) {
        const float* pp = p4 + ((size_t)b * 200 + c) * 4;
        float v0 = pp[0], v1 = pp[1], v2 = pp[2], v3 = pp[3];
#pragma unroll
        for (int o = 0; o < 4; ++o) {
            const float* fw = fcw + (o * 200 + c) * 4;
            pa[o] += fw[0] * v0 + fw[1] * v1 + fw[2] * v2 + fw[3] * v3;
        }
    }
#pragma unroll
    for (int o = 0; o < 4; ++o) red[o][j] = pa[o];
    __syncthreads();
    for (int s = 64; s > 0; s >>= 1) {
        if (j < s) {
#pragma unroll
            for (int o = 0; o < 4; ++o) red[o][j] += red[o][j + s];
        }
        __syncthreads();
    }
    if (j < 4) fs[j] = red[j][0] + fcb[j];
    __syncthreads();

    int cid = cids[b];
    float hvv = hb1[cid * 128 + j];
#pragma unroll
    for (int f = 0; f < 4; ++f) hvv += fs[f] * hW1[(cid * 4 + f) * 128 + j];
    hvv = fmaxf(hvv, 0.f);
#pragma unroll
    for (int o = 0; o < 4; ++o) red[o][j] = hvv * hW2[(cid * 128 + j) * 4 + o];
    __syncthreads();
    for (int s = 64; s > 0; s >>= 1) {
        if (j < s) {
#pragma unroll
            for (int o = 0; o < 4; ++o) red[o][j] += red[o][j + s];
        }
        __syncthreads();
    }
    if (j < 4) out[b * 4 + j] = red[j][0] + hb2[cid * 4 + j];
}

// ---------------- launch ----------------
extern "C" void kernel_launch(void* const* d_in, const int* in_sizes, int n_in,
                              void* d_out, int out_size, void* d_ws, size_t ws_size,
                              hipStream_t stream) {
    (void)in_sizes; (void)n_in; (void)out_size; (void)ws_size;
    const float* x    = (const float*)d_in[0];
    const int*   cid  = (const int*)d_in[1];
    const float* ctw  = (const float*)d_in[2];
    const float* ctb  = (const float*)d_in[3];
    const float* csw  = (const float*)d_in[4];
    const float* g1 = (const float*)d_in[5],  *b1 = (const float*)d_in[6];
    const float* m1 = (const float*)d_in[7],  *v1 = (const float*)d_in[8];
    const float* w2 = (const float*)d_in[9];
    const float* g2 = (const float*)d_in[10], *b2 = (const float*)d_in[11];
    const float* m2 = (const float*)d_in[12], *v2 = (const float*)d_in[13];
    const float* w3 = (const float*)d_in[14];
    const float* g3 = (const float*)d_in[15], *b3 = (const float*)d_in[16];
    const float* m3 = (const float*)d_in[17], *v3 = (const float*)d_in[18];
    const float* w4 = (const float*)d_in[19];
    const float* g4 = (const float*)d_in[20], *b4 = (const float*)d_in[21];
    const float* m4 = (const float*)d_in[22], *v4 = (const float*)d_in[23];
    const float* fcw = (const float*)d_in[24], *fcb = (const float*)d_in[25];
    const float* hW1 = (const float*)d_in[26], *hb1 = (const float*)d_in[27];
    const float* hW2 = (const float*)d_in[28], *hb2 = (const float*)d_in[29];
    float* ws  = (float*)d_ws;
    float* out = (float*)d_out;

    k_pre2<<<dim3((N_WTOT + 512 + 255) / 256), dim3(256), 0, stream>>>(
        ctw, ctb, csw, g1, b1, m1, v1, w2, g2, b2, m2, v2,
        w3, g3, b3, m3, v3, w4, g4, b4, m4, v4, ws);
    k_conv1<<<dim3(8, 128), dim3(256), 0, stream>>>(x, ws);
    k_gemm2<<<dim3(316), dim3(256), 0, stream>>>(ws);
    k_gemm3<<<dim3(92),  dim3(256), 0, stream>>>(ws);
    k_gemm4<<<dim3(104), dim3(256), 0, stream>>>(ws);
    k_heads<<<dim3(128), dim3(128), 0, stream>>>(ws, fcw, fcb, cid,
                                                 hW1, hb1, hW2, hb2, out);
}